// Round 1
// baseline (2385.768 us; speedup 1.0000x reference)
//
#include <hip/hip_runtime.h>
#include <math.h>

// TemporalGraphTower on MI355X (gfx950).
// B=8192 events, NODE_DIM=128, EDGE_DIM=64, TIME_DIM=32, HIDDEN=256, K=20,
// IN_DIM=352, N_LAYERS=2, N_NODES=100000.
//
// Precision plan (threshold 2e-2, time2vec linear term ~1e3 => hidden ~50-350):
//  - M1 (x[352]@W1): bf16 MFMA, large time column zeroed in bf16 tile and
//    applied as exact fp32 rank-1 update.
//  - M2 (relu(h)@W2), GRU matmuls: hi/lo bf16 split both operands, 3 MFMAs.
//  - Everything else fp32.

typedef __bf16 bf16;
typedef __bf16 bf16x8 __attribute__((ext_vector_type(8)));
typedef float f32x4 __attribute__((ext_vector_type(4)));

#define MFMA16(a, b, c) __builtin_amdgcn_mfma_f32_16x16x32_bf16((a), (b), (c), 0, 0, 0)

__device__ __forceinline__ void split2(float v, bf16& hi, bf16& lo) {
  hi = (bf16)v;
  lo = (bf16)(v - (float)hi);
}

#define NB_EV 8192
#define KNB 20
#define ROWS_NB (NB_EV * KNB)   // 163840
#define IN_DIM 352
#define HID 256
#define ND 128

// ---------------- prep: weight transposes / bf16 splits ----------------
// W1T  bf16 [2][256][352]   (B-operand wants k-contiguous per output col)
// W2T  hi/lo bf16 [2][128][256]
// wih/whh hi/lo bf16 [384][128] (already [n][k] layout)
// w320 f32 [2][256] = W1[l][320][:]
__global__ void k_prep_weights(const float* __restrict__ W1, const float* __restrict__ W2,
                               const float* __restrict__ wih, const float* __restrict__ whh,
                               bf16* __restrict__ W1T, bf16* __restrict__ W2Thi, bf16* __restrict__ W2Tlo,
                               bf16* __restrict__ wihhi, bf16* __restrict__ wihlo,
                               bf16* __restrict__ whhhi, bf16* __restrict__ whhlo,
                               float* __restrict__ w320) {
  const int N1 = 2 * 256 * 352;   // 180224
  const int N2 = 2 * 128 * 256;   // 65536
  const int N3 = 384 * 128;       // 49152
  int total = N1 + N2 + N3 + N3 + 512;
  for (int i = blockIdx.x * blockDim.x + threadIdx.x; i < total; i += gridDim.x * blockDim.x) {
    int j = i;
    if (j < N1) {
      int l = j / 90112; int r = j - l * 90112; int n = r / 352; int k = r - n * 352;
      W1T[j] = (bf16)W1[(l * 352 + k) * 256 + n];
    } else if ((j -= N1) < N2) {
      int l = j / 32768; int r = j - l * 32768; int n = r / 256; int k = r - n * 256;
      bf16 hi, lo; split2(W2[(l * 256 + k) * 128 + n], hi, lo);
      W2Thi[j] = hi; W2Tlo[j] = lo;
    } else if ((j -= N2) < N3) {
      bf16 hi, lo; split2(wih[j], hi, lo); wihhi[j] = hi; wihlo[j] = lo;
    } else if ((j -= N3) < N3) {
      bf16 hi, lo; split2(whh[j], hi, lo); whhhi[j] = hi; whhlo[j] = lo;
    } else {
      j -= N3;
      int l = j >> 8, n = j & 255;
      w320[j] = W1[(l * 352 + 320) * 256 + n];
    }
  }
}

// time2vec table [B][32], initial embedding gathers, zero nb accumulators
__global__ void k_prep_misc(const float* __restrict__ ts, const float* __restrict__ w0,
                            const float* __restrict__ b0, const float* __restrict__ w,
                            const float* __restrict__ bb,
                            const int* __restrict__ srcn, const int* __restrict__ dstn,
                            const float* __restrict__ memory,
                            float* __restrict__ time_emb, float* __restrict__ embA0,
                            float* __restrict__ embB0, float* __restrict__ nb_out) {
  const int N1 = NB_EV * 32, N2 = NB_EV * ND, N3 = 4 * NB_EV * ND;
  int total = N1 + N2 + N3;
  float w0v = w0[0], b0v = b0[0];
  for (int i = blockIdx.x * blockDim.x + threadIdx.x; i < total; i += gridDim.x * blockDim.x) {
    int j = i;
    if (j < N1) {
      int b = j >> 5, c = j & 31;
      float t = ts[b];
      time_emb[j] = (c == 0) ? (w0v * t + b0v) : sinf(w[c - 1] * t + bb[c - 1]);
    } else if ((j -= N1) < N2) {
      int b = j >> 7, c = j & 127;
      embA0[j] = memory[(long)srcn[b] * ND + c];
      embB0[j] = memory[(long)dstn[b] * ND + c];
    } else {
      nb_out[j - N2] = 0.f;
    }
  }
}

// edge_enc[b][j] = sum_k edge_attrs[b][k]*enc_W[k][j] + enc_b[j]
__global__ void k_edge(const float* __restrict__ ea, const float* __restrict__ encW,
                       const float* __restrict__ encb, float* __restrict__ out) {
  __shared__ float row[64];
  int b = blockIdx.x, j = threadIdx.x;
  row[j] = ea[b * 64 + j];
  __syncthreads();
  float s = encb[j];
#pragma unroll
  for (int k = 0; k < 64; ++k) s += row[k] * encW[k * 64 + j];
  out[b * 64 + j] = s;
}

// ---------------- fused neighbor gather + MLP + mean ----------------
// grid: (2560, 4) -- z = layer*2 + side ; 64 rows (=(b,k) pairs) per block, 256 threads.
#define XSS 360   // x LDS stride (bf16), 720B rows -> 2-way-free banks
#define HSS 264   // h LDS stride
#define MSS_NB 132
__global__ __launch_bounds__(256) void k_neighbor(
    const int* __restrict__ srcn, const int* __restrict__ dstn,
    const float* __restrict__ memory, const int* __restrict__ nbids,
    const float* __restrict__ nbt, const float* __restrict__ nbe,
    const float* __restrict__ w0p, const float* __restrict__ b0p,
    const float* __restrict__ wp, const float* __restrict__ bp,
    const bf16* __restrict__ W1T, const float* __restrict__ w320, const float* __restrict__ b1,
    const bf16* __restrict__ W2Thi, const bf16* __restrict__ W2Tlo, const float* __restrict__ b2,
    float* __restrict__ nb_out) {
  __shared__ __align__(16) char smem[68864];
  bf16* xs = (bf16*)smem;                 // [64][360], overlaid later by h planes / msgs
  bf16* hhi = (bf16*)smem;                // [64][264]
  bf16* hlo = (bf16*)(smem + 33792);      // [64][264]
  float* msgs = (float*)smem;             // [64][132]
  int* nbid_l = (int*)(smem + 67584);
  int* n_l = nbid_l + 64;
  int* flat_l = n_l + 64;
  float* t_l = (float*)(flat_l + 64);
  float* c_l = t_l + 64;

  const int tid = threadIdx.x;
  const int z = blockIdx.y;
  const int layer = z >> 1, side = z & 1;
  const int r0 = blockIdx.x * 64;
  const int* nodes = side ? dstn : srcn;

  if (tid < 64) {
    int rg = r0 + tid;
    int b = rg / 20, k = rg - b * 20;
    int n = nodes[b];
    int flat = n * 20 + k;
    nbid_l[tid] = nbids[flat];
    n_l[tid] = n;
    flat_l[tid] = flat;
    float t = nbt[flat];
    t_l[tid] = t;
    c_l[tid] = w0p[0] * t + b0p[0];
  }
  __syncthreads();

  // build x tile: [nb_emb(128) | node_mem(128) | nb_e(64) | t2v(32, col0 zeroed)]
  for (int task = tid; task < 64 * 88; task += 256) {
    int r = task / 88; int c = (task - r * 88) * 4;
    float4 v;
    if (c < 128) {
      v = *(const float4*)&memory[(long)nbid_l[r] * ND + c];
    } else if (c < 256) {
      v = *(const float4*)&memory[(long)n_l[r] * ND + (c - 128)];
    } else if (c < 320) {
      v = *(const float4*)&nbe[(long)flat_l[r] * 64 + (c - 256)];
    } else {
      float t = t_l[r];
      float vv[4];
#pragma unroll
      for (int q = 0; q < 4; ++q) {
        int cc = c + q - 320;
        vv[q] = (cc == 0) ? 0.f : sinf(wp[cc - 1] * t + bp[cc - 1]);
      }
      v = make_float4(vv[0], vv[1], vv[2], vv[3]);
    }
    union { bf16 h[4]; uint2 u; } pk;
    pk.h[0] = (bf16)v.x; pk.h[1] = (bf16)v.y; pk.h[2] = (bf16)v.z; pk.h[3] = (bf16)v.w;
    *(uint2*)&xs[r * XSS + c] = pk.u;
  }
  __syncthreads();

  const int wid = tid >> 6, lane = tid & 63;
  const int col = lane & 15, ko8 = (lane >> 4) * 8;
  const int rb = wid * 16;
  const int rowA = rb + col;
  const int rbase = rb + (lane >> 4) * 4;
  const bf16* W1Tl = W1T + layer * 90112;

  // M1: h = x @ W1 (bf16), B streamed from L2
  f32x4 acc[16];
#pragma unroll
  for (int nt = 0; nt < 16; ++nt) acc[nt] = (f32x4){0.f, 0.f, 0.f, 0.f};
#pragma unroll
  for (int k0 = 0; k0 < IN_DIM; k0 += 32) {
    bf16x8 a = *(const bf16x8*)&xs[rowA * XSS + k0 + ko8];
    const bf16* wb = W1Tl + k0 + ko8;
#pragma unroll
    for (int nt = 0; nt < 16; ++nt) {
      bf16x8 bfr = *(const bf16x8*)(wb + (nt * 16 + col) * IN_DIM);
      acc[nt] = MFMA16(a, bfr, acc[nt]);
    }
  }
  __syncthreads();  // xs dead -> overlay h planes

  // rank-1 time fix + bias + relu + hi/lo split into LDS
  const float* b1l = b1 + layer * 256;
  const float* w320l = w320 + layer * 256;
#pragma unroll
  for (int nt = 0; nt < 16; ++nt) {
    int cc = nt * 16 + col;
    float wv = w320l[cc], bv = b1l[cc];
#pragma unroll
    for (int i = 0; i < 4; ++i) {
      int rr = rbase + i;
      float v = acc[nt][i] + c_l[rr] * wv + bv;
      v = fmaxf(v, 0.f);
      bf16 hi, lo; split2(v, hi, lo);
      hhi[rr * HSS + cc] = hi;
      hlo[rr * HSS + cc] = lo;
    }
  }
  __syncthreads();

  // M2: msgs = relu(h) @ W2, hi/lo x hi/lo (3 products)
  const bf16* W2hl = W2Thi + layer * 32768;
  const bf16* W2ll = W2Tlo + layer * 32768;
  f32x4 acc2[8];
#pragma unroll
  for (int nt = 0; nt < 8; ++nt) acc2[nt] = (f32x4){0.f, 0.f, 0.f, 0.f};
#pragma unroll
  for (int k0 = 0; k0 < HID; k0 += 32) {
    bf16x8 ahi = *(const bf16x8*)&hhi[rowA * HSS + k0 + ko8];
    bf16x8 alo = *(const bf16x8*)&hlo[rowA * HSS + k0 + ko8];
#pragma unroll
    for (int nt = 0; nt < 8; ++nt) {
      int n = nt * 16 + col;
      bf16x8 bhi = *(const bf16x8*)(W2hl + n * HID + k0 + ko8);
      bf16x8 blo = *(const bf16x8*)(W2ll + n * HID + k0 + ko8);
      acc2[nt] = MFMA16(ahi, bhi, acc2[nt]);
      acc2[nt] = MFMA16(ahi, blo, acc2[nt]);
      acc2[nt] = MFMA16(alo, bhi, acc2[nt]);
    }
  }
  __syncthreads();  // h planes dead -> overlay msgs

  const float* b2l = b2 + layer * 128;
#pragma unroll
  for (int nt = 0; nt < 8; ++nt) {
    int cc = nt * 16 + col;
    float bv = b2l[cc];
#pragma unroll
    for (int i = 0; i < 4; ++i)
      msgs[(rbase + i) * MSS_NB + cc] = (acc2[nt][i] + bv) * 0.05f;  // /K=20
  }
  __syncthreads();

  // reduce over k within tile, atomic-accumulate per event b
  {
    int colr = tid & 127, half = tid >> 7;
    int bf0 = r0 / 20;
    for (int bi = half; bi <= 4; bi += 2) {
      int b = bf0 + bi;
      if (b >= NB_EV) break;
      int rlo = b * 20 - r0, rhi = rlo + 20;
      rlo = max(rlo, 0); rhi = min(rhi, 64);
      if (rlo >= rhi) continue;
      float s = 0.f;
      for (int r = rlo; r < rhi; ++r) s += msgs[r * MSS_NB + colr];
      atomicAdd(&nb_out[((long)((layer * 2 + side) * NB_EV + b)) * ND + colr], s);
    }
  }
}

// ---------------- event chain: MLP + GRU (one launch per layer) ----------------
#define MSS_EV 136
__global__ __launch_bounds__(256) void k_event(
    int layer, const float* __restrict__ embA_in, const float* __restrict__ embB_in,
    float* __restrict__ outA, int ostrideA, float* __restrict__ outB, int ostrideB,
    const float* __restrict__ time_emb, const float* __restrict__ edge_enc,
    const bf16* __restrict__ W1T, const float* __restrict__ w320, const float* __restrict__ b1,
    const bf16* __restrict__ W2Thi, const bf16* __restrict__ W2Tlo, const float* __restrict__ b2,
    const float* __restrict__ nb_out,
    const bf16* __restrict__ wihhi, const bf16* __restrict__ wihlo,
    const bf16* __restrict__ whhhi, const bf16* __restrict__ whhlo,
    const float* __restrict__ bih, const float* __restrict__ bhh) {
  __shared__ __align__(16) char smem[102656];
  bf16* xs = (bf16*)smem;                        // [64][360]
  bf16* hhi = (bf16*)smem;                       // [64][264]
  bf16* hlo = (bf16*)(smem + 33792);
  bf16* mhi = (bf16*)smem;                       // [64][136]
  bf16* mlo = (bf16*)(smem + 17408);
  bf16* ghi = (bf16*)(smem + 67584);             // GRU h planes [64][136]
  bf16* glo = (bf16*)(smem + 67584 + 17408);
  float* c_l = (float*)(smem + 102400);

  const int tid = threadIdx.x;
  const int r0 = blockIdx.x * 64;
  const int side = r0 >> 13;                     // uniform per block
  const int b0r = r0 & (NB_EV - 1);
  const float* ea = side ? embB_in : embA_in;    // own embedding (GRU h)
  const float* eb = side ? embA_in : embB_in;

  if (tid < 64) c_l[tid] = time_emb[(b0r + tid) * 32];

  for (int task = tid; task < 64 * 88; task += 256) {
    int r = task / 88; int c = (task - r * 88) * 4;
    int b = b0r + r;
    float4 v;
    if (c < 128) {
      v = *(const float4*)&ea[(long)b * ND + c];
      bf16 h0, l0, h1, l1, h2, l2, h3, l3;
      split2(v.x, h0, l0); split2(v.y, h1, l1); split2(v.z, h2, l2); split2(v.w, h3, l3);
      ghi[r * MSS_EV + c + 0] = h0; glo[r * MSS_EV + c + 0] = l0;
      ghi[r * MSS_EV + c + 1] = h1; glo[r * MSS_EV + c + 1] = l1;
      ghi[r * MSS_EV + c + 2] = h2; glo[r * MSS_EV + c + 2] = l2;
      ghi[r * MSS_EV + c + 3] = h3; glo[r * MSS_EV + c + 3] = l3;
    } else if (c < 256) {
      v = *(const float4*)&eb[(long)b * ND + (c - 128)];
    } else if (c < 320) {
      v = *(const float4*)&edge_enc[(long)b * 64 + (c - 256)];
    } else {
      float vv[4];
#pragma unroll
      for (int q = 0; q < 4; ++q) {
        int cc = c + q - 320;
        vv[q] = (cc == 0) ? 0.f : time_emb[b * 32 + cc];
      }
      v = make_float4(vv[0], vv[1], vv[2], vv[3]);
    }
    union { bf16 h[4]; uint2 u; } pk;
    pk.h[0] = (bf16)v.x; pk.h[1] = (bf16)v.y; pk.h[2] = (bf16)v.z; pk.h[3] = (bf16)v.w;
    *(uint2*)&xs[r * XSS + c] = pk.u;
  }
  __syncthreads();

  const int wid = tid >> 6, lane = tid & 63;
  const int col = lane & 15, ko8 = (lane >> 4) * 8;
  const int rb = wid * 16;
  const int rowA = rb + col;
  const int rbase = rb + (lane >> 4) * 4;
  const bf16* W1Tl = W1T + layer * 90112;

  f32x4 acc[16];
#pragma unroll
  for (int nt = 0; nt < 16; ++nt) acc[nt] = (f32x4){0.f, 0.f, 0.f, 0.f};
#pragma unroll
  for (int k0 = 0; k0 < IN_DIM; k0 += 32) {
    bf16x8 a = *(const bf16x8*)&xs[rowA * XSS + k0 + ko8];
    const bf16* wb = W1Tl + k0 + ko8;
#pragma unroll
    for (int nt = 0; nt < 16; ++nt) {
      bf16x8 bfr = *(const bf16x8*)(wb + (nt * 16 + col) * IN_DIM);
      acc[nt] = MFMA16(a, bfr, acc[nt]);
    }
  }
  __syncthreads();

  const float* b1l = b1 + layer * 256;
  const float* w320l = w320 + layer * 256;
#pragma unroll
  for (int nt = 0; nt < 16; ++nt) {
    int cc = nt * 16 + col;
    float wv = w320l[cc], bv = b1l[cc];
#pragma unroll
    for (int i = 0; i < 4; ++i) {
      int rr = rbase + i;
      float v = acc[nt][i] + c_l[rr] * wv + bv;
      v = fmaxf(v, 0.f);
      bf16 hi, lo; split2(v, hi, lo);
      hhi[rr * HSS + cc] = hi;
      hlo[rr * HSS + cc] = lo;
    }
  }
  __syncthreads();

  const bf16* W2hl = W2Thi + layer * 32768;
  const bf16* W2ll = W2Tlo + layer * 32768;
  f32x4 acc2[8];
#pragma unroll
  for (int nt = 0; nt < 8; ++nt) acc2[nt] = (f32x4){0.f, 0.f, 0.f, 0.f};
#pragma unroll
  for (int k0 = 0; k0 < HID; k0 += 32) {
    bf16x8 ahi = *(const bf16x8*)&hhi[rowA * HSS + k0 + ko8];
    bf16x8 alo = *(const bf16x8*)&hlo[rowA * HSS + k0 + ko8];
#pragma unroll
    for (int nt = 0; nt < 8; ++nt) {
      int n = nt * 16 + col;
      bf16x8 bhi = *(const bf16x8*)(W2hl + n * HID + k0 + ko8);
      bf16x8 blo = *(const bf16x8*)(W2ll + n * HID + k0 + ko8);
      acc2[nt] = MFMA16(ahi, bhi, acc2[nt]);
      acc2[nt] = MFMA16(ahi, blo, acc2[nt]);
      acc2[nt] = MFMA16(alo, bhi, acc2[nt]);
    }
  }
  __syncthreads();  // h planes dead -> overlay m planes

  const float* b2l = b2 + layer * 128;
  const float* nbl = nb_out + ((long)(layer * 2 + side)) * NB_EV * ND;
#pragma unroll
  for (int nt = 0; nt < 8; ++nt) {
    int cc = nt * 16 + col;
    float bv = b2l[cc];
#pragma unroll
    for (int i = 0; i < 4; ++i) {
      int rr = rbase + i;
      float mval = acc2[nt][i] + bv + nbl[(long)(b0r + rr) * ND + cc];
      bf16 hi, lo; split2(mval, hi, lo);
      mhi[rr * MSS_EV + cc] = hi;
      mlo[rr * MSS_EV + cc] = lo;
    }
  }
  __syncthreads();

  // GRU: gx = m@w_ih^T + b_ih ; gh = h@w_hh^T + b_hh ; gates (r,z,n)
  float* outP = side ? outB : outA;
  const int ostride = side ? ostrideB : ostrideA;
  for (int jt = 0; jt < 8; ++jt) {
    f32x4 gx[3], gh[3];
#pragma unroll
    for (int g = 0; g < 3; ++g) {
      gx[g] = (f32x4){0.f, 0.f, 0.f, 0.f};
      gh[g] = (f32x4){0.f, 0.f, 0.f, 0.f};
    }
#pragma unroll
    for (int k0 = 0; k0 < ND; k0 += 32) {
      bf16x8 amh = *(const bf16x8*)&mhi[rowA * MSS_EV + k0 + ko8];
      bf16x8 aml = *(const bf16x8*)&mlo[rowA * MSS_EV + k0 + ko8];
      bf16x8 ahh = *(const bf16x8*)&ghi[rowA * MSS_EV + k0 + ko8];
      bf16x8 ahl = *(const bf16x8*)&glo[rowA * MSS_EV + k0 + ko8];
#pragma unroll
      for (int g = 0; g < 3; ++g) {
        int n = g * 128 + jt * 16 + col;
        bf16x8 bh = *(const bf16x8*)(wihhi + n * ND + k0 + ko8);
        bf16x8 bl = *(const bf16x8*)(wihlo + n * ND + k0 + ko8);
        gx[g] = MFMA16(amh, bh, gx[g]);
        gx[g] = MFMA16(aml, bh, gx[g]);
        gx[g] = MFMA16(amh, bl, gx[g]);
        bf16x8 ch = *(const bf16x8*)(whhhi + n * ND + k0 + ko8);
        bf16x8 cl2 = *(const bf16x8*)(whhlo + n * ND + k0 + ko8);
        gh[g] = MFMA16(ahh, ch, gh[g]);
        gh[g] = MFMA16(ahl, ch, gh[g]);
        gh[g] = MFMA16(ahh, cl2, gh[g]);
      }
    }
    int j = jt * 16 + col;
    float bihr = bih[j], bihz = bih[128 + j], bihn = bih[256 + j];
    float bhhr = bhh[j], bhhz = bhh[128 + j], bhhn = bhh[256 + j];
#pragma unroll
    for (int i = 0; i < 4; ++i) {
      int rr = rbase + i;
      float rx = gx[0][i] + bihr, zx = gx[1][i] + bihz, nx = gx[2][i] + bihn;
      float rh = gh[0][i] + bhhr, zh = gh[1][i] + bhhz, nh = gh[2][i] + bhhn;
      float r = 1.f / (1.f + expf(-(rx + rh)));
      float zz = 1.f / (1.f + expf(-(zx + zh)));
      float n = tanhf(nx + r * nh);
      float hval = (float)ghi[rr * MSS_EV + j] + (float)glo[rr * MSS_EV + j];
      outP[(long)(b0r + rr) * ostride + j] = (1.f - zz) * n + zz * hval;
    }
  }
}

// ---------------- launch ----------------
extern "C" void kernel_launch(void* const* d_in, const int* in_sizes, int n_in,
                              void* d_out, int out_size, void* d_ws, size_t ws_size,
                              hipStream_t stream) {
  const int* srcn = (const int*)d_in[0];
  const int* dstn = (const int*)d_in[1];
  const float* edge_attrs = (const float*)d_in[2];
  const float* timestamps = (const float*)d_in[3];
  const float* memory = (const float*)d_in[4];
  const int* neighbor_ids = (const int*)d_in[5];
  const float* neighbor_times = (const float*)d_in[6];
  const float* neighbor_edge_attrs = (const float*)d_in[7];
  const float* t2v_w0 = (const float*)d_in[8];
  const float* t2v_b0 = (const float*)d_in[9];
  const float* t2v_w = (const float*)d_in[10];
  const float* t2v_b = (const float*)d_in[11];
  const float* enc_W = (const float*)d_in[12];
  const float* enc_b = (const float*)d_in[13];
  const float* mlp_W1 = (const float*)d_in[14];
  const float* mlp_b1 = (const float*)d_in[15];
  const float* mlp_W2 = (const float*)d_in[16];
  const float* mlp_b2 = (const float*)d_in[17];
  const float* gru_w_ih = (const float*)d_in[18];
  const float* gru_w_hh = (const float*)d_in[19];
  const float* gru_b_ih = (const float*)d_in[20];
  const float* gru_b_hh = (const float*)d_in[21];

  char* ws = (char*)d_ws;
  size_t off = 0;
  auto alloc = [&](size_t bytes) { size_t o = off; off += (bytes + 255) & ~(size_t)255; return o; };
  bf16* W1T = (bf16*)(ws + alloc(2 * 256 * 352 * 2));
  bf16* W2Thi = (bf16*)(ws + alloc(2 * 128 * 256 * 2));
  bf16* W2Tlo = (bf16*)(ws + alloc(2 * 128 * 256 * 2));
  bf16* wihhi = (bf16*)(ws + alloc(384 * 128 * 2));
  bf16* wihlo = (bf16*)(ws + alloc(384 * 128 * 2));
  bf16* whhhi = (bf16*)(ws + alloc(384 * 128 * 2));
  bf16* whhlo = (bf16*)(ws + alloc(384 * 128 * 2));
  float* w320 = (float*)(ws + alloc(512 * 4));
  float* time_emb = (float*)(ws + alloc((size_t)NB_EV * 32 * 4));
  float* edge_enc = (float*)(ws + alloc((size_t)NB_EV * 64 * 4));
  float* embA0 = (float*)(ws + alloc((size_t)NB_EV * ND * 4));
  float* embB0 = (float*)(ws + alloc((size_t)NB_EV * ND * 4));
  float* embA1 = (float*)(ws + alloc((size_t)NB_EV * ND * 4));
  float* embB1 = (float*)(ws + alloc((size_t)NB_EV * ND * 4));
  float* nb_out = (float*)(ws + alloc((size_t)4 * NB_EV * ND * 4));

  k_prep_weights<<<512, 256, 0, stream>>>(mlp_W1, mlp_W2, gru_w_ih, gru_w_hh,
                                          W1T, W2Thi, W2Tlo, wihhi, wihlo, whhhi, whhlo, w320);
  k_prep_misc<<<2048, 256, 0, stream>>>(timestamps, t2v_w0, t2v_b0, t2v_w, t2v_b,
                                        srcn, dstn, memory, time_emb, embA0, embB0, nb_out);
  k_edge<<<NB_EV, 64, 0, stream>>>(edge_attrs, enc_W, enc_b, edge_enc);

  k_neighbor<<<dim3(ROWS_NB / 64, 4, 1), 256, 0, stream>>>(
      srcn, dstn, memory, neighbor_ids, neighbor_times, neighbor_edge_attrs,
      t2v_w0, t2v_b0, t2v_w, t2v_b, W1T, w320, mlp_b1, W2Thi, W2Tlo, mlp_b2, nb_out);

  k_event<<<2 * NB_EV / 64, 256, 0, stream>>>(
      0, embA0, embB0, embA1, ND, embB1, ND, time_emb, edge_enc,
      W1T, w320, mlp_b1, W2Thi, W2Tlo, mlp_b2, nb_out,
      wihhi, wihlo, whhhi, whhlo, gru_b_ih, gru_b_hh);

  float* outf = (float*)d_out;
  k_event<<<2 * NB_EV / 64, 256, 0, stream>>>(
      1, embA1, embB1, outf, 2 * ND, outf + ND, 2 * ND, time_emb, edge_enc,
      W1T, w320, mlp_b1, W2Thi, W2Tlo, mlp_b2, nb_out,
      wihhi, wihlo, whhhi, whhlo, gru_b_ih, gru_b_hh);
}

// Round 2
// 917.929 us; speedup vs baseline: 2.5991x; 2.5991x over previous
//
#include <hip/hip_runtime.h>
#include <math.h>

// TemporalGraphTower on MI355X (gfx950) — round 2.
// Neighbor path restructured: build-X (blocked/swizzled) + proper MFMA GEMM
// with global_load_lds staging and 4x4 register blocking.

typedef __bf16 bf16;
typedef __bf16 bf16x8 __attribute__((ext_vector_type(8)));
typedef float f32x4 __attribute__((ext_vector_type(4)));

#define MFMA16(a, b, c) __builtin_amdgcn_mfma_f32_16x16x32_bf16((a), (b), (c), 0, 0, 0)

__device__ __forceinline__ void split2(float v, bf16& hi, bf16& lo) {
  hi = (bf16)v;
  lo = (bf16)(v - (float)hi);
}

typedef const __attribute__((address_space(1))) unsigned int* gptr_t;
typedef __attribute__((address_space(3))) unsigned int* lptr_t;
__device__ __forceinline__ void stage16(const void* g, void* l) {
  __builtin_amdgcn_global_load_lds((gptr_t)g, (lptr_t)l, 16, 0, 0);
}

#define NB_EV 8192
#define KNB 20
#define ROWS_NB (NB_EV * KNB)   // 163840
#define IN_DIM 352
#define HID 256
#define ND 128

// ---------------- prep: weight transposes / bf16 splits / blocked layouts ----------------
// W1T  bf16 [2][256][352]       (for event kernel streaming)
// W2T  hi/lo bf16 [2][128][256]
// wih/whh hi/lo bf16 [384][128]
// w320 f32 [2][256]
// W1blk bf16 [2][11 k0][256n x 32k swizzled]   slice = 8192 elems (16KB)
// W2blk bf16 [2][2 plane][8 k0][128n x 32k swizzled] slice = 4096 elems (8KB)
__global__ void k_prep_weights(const float* __restrict__ W1, const float* __restrict__ W2,
                               const float* __restrict__ wih, const float* __restrict__ whh,
                               bf16* __restrict__ W1T, bf16* __restrict__ W2Thi, bf16* __restrict__ W2Tlo,
                               bf16* __restrict__ wihhi, bf16* __restrict__ wihlo,
                               bf16* __restrict__ whhhi, bf16* __restrict__ whhlo,
                               float* __restrict__ w320,
                               bf16* __restrict__ W1blk, bf16* __restrict__ W2blk, int do_blk) {
  const int N1 = 2 * 256 * 352;   // 180224
  const int N2 = 2 * 128 * 256;   // 65536
  const int N3 = 384 * 128;       // 49152
  const int NB1 = 2 * 11 * 8192;  // 180224
  const int NB2 = 2 * 2 * 8 * 4096; // 131072
  int total = N1 + N2 + N3 + N3 + 512 + (do_blk ? (NB1 + NB2) : 0);
  for (int i = blockIdx.x * blockDim.x + threadIdx.x; i < total; i += gridDim.x * blockDim.x) {
    int j = i;
    if (j < N1) {
      int l = j / 90112; int r = j - l * 90112; int n = r / 352; int k = r - n * 352;
      W1T[j] = (bf16)W1[(l * 352 + k) * 256 + n];
    } else if ((j -= N1) < N2) {
      int l = j / 32768; int r = j - l * 32768; int n = r / 256; int k = r - n * 256;
      bf16 hi, lo; split2(W2[(l * 256 + k) * 128 + n], hi, lo);
      W2Thi[j] = hi; W2Tlo[j] = lo;
    } else if ((j -= N2) < N3) {
      bf16 hi, lo; split2(wih[j], hi, lo); wihhi[j] = hi; wihlo[j] = lo;
    } else if ((j -= N3) < N3) {
      bf16 hi, lo; split2(whh[j], hi, lo); whhhi[j] = hi; whhlo[j] = lo;
    } else if ((j -= N3) < 512) {
      int l = j >> 8, n = j & 255;
      w320[j] = W1[(l * 352 + 320) * 256 + n];
    } else if ((j -= 512) < NB1) {
      int l = j / 90112, r = j - l * 90112, k0 = r / 8192, s = r - k0 * 8192;
      int p = s >> 3, off = s & 7;
      int n = p >> 2, sw = p & 3, c16 = sw ^ ((n >> 1) & 3);
      int k = k0 * 32 + c16 * 8 + off;
      W1blk[j] = (bf16)W1[(l * 352 + k) * 256 + n];
    } else {
      j -= NB1;
      int l = j >> 16, rem = j & 65535, plane = rem >> 15, rem2 = rem & 32767;
      int k0 = rem2 >> 12, s = rem2 & 4095;
      int p = s >> 3, off = s & 7;
      int n = p >> 2, sw = p & 3, c16 = sw ^ ((n >> 1) & 3);
      int k = k0 * 32 + c16 * 8 + off;
      bf16 hi, lo; split2(W2[(l * 256 + k) * 128 + n], hi, lo);
      W2blk[j] = plane ? lo : hi;
    }
  }
}

// time2vec table [B][32], initial embedding gathers, zero nb accumulators
__global__ void k_prep_misc(const float* __restrict__ ts, const float* __restrict__ w0,
                            const float* __restrict__ b0, const float* __restrict__ w,
                            const float* __restrict__ bb,
                            const int* __restrict__ srcn, const int* __restrict__ dstn,
                            const float* __restrict__ memory,
                            float* __restrict__ time_emb, float* __restrict__ embA0,
                            float* __restrict__ embB0, float* __restrict__ nb_out) {
  const int N1 = NB_EV * 32, N2 = NB_EV * ND, N3 = 4 * NB_EV * ND;
  int total = N1 + N2 + N3;
  float w0v = w0[0], b0v = b0[0];
  for (int i = blockIdx.x * blockDim.x + threadIdx.x; i < total; i += gridDim.x * blockDim.x) {
    int j = i;
    if (j < N1) {
      int b = j >> 5, c = j & 31;
      float t = ts[b];
      time_emb[j] = (c == 0) ? (w0v * t + b0v) : sinf(w[c - 1] * t + bb[c - 1]);
    } else if ((j -= N1) < N2) {
      int b = j >> 7, c = j & 127;
      embA0[j] = memory[(long)srcn[b] * ND + c];
      embB0[j] = memory[(long)dstn[b] * ND + c];
    } else {
      nb_out[j - N2] = 0.f;
    }
  }
}

// edge_enc[b][j] = sum_k edge_attrs[b][k]*enc_W[k][j] + enc_b[j]
__global__ void k_edge(const float* __restrict__ ea, const float* __restrict__ encW,
                       const float* __restrict__ encb, float* __restrict__ out) {
  __shared__ float row[64];
  int b = blockIdx.x, j = threadIdx.x;
  row[j] = ea[b * 64 + j];
  __syncthreads();
  float s = encb[j];
#pragma unroll
  for (int k = 0; k < 64; ++k) s += row[k] * encW[k * 64 + j];
  out[b * 64 + j] = s;
}

// ---------------- build X (blocked, swizzled) + c_l ----------------
// Xblk: [side][2560 blk][11 k0][64r x 32k swizzled] slice = 2048 elems (4KB)
// swizzle: 16B-chunk p = r*4 + (c16 ^ ((r>>1)&3))
__global__ __launch_bounds__(256) void k_build_x(
    const int* __restrict__ srcn, const int* __restrict__ dstn,
    const float* __restrict__ memory, const int* __restrict__ nbids,
    const float* __restrict__ nbt, const float* __restrict__ nbe,
    const float* __restrict__ w0p, const float* __restrict__ b0p,
    const float* __restrict__ wp, const float* __restrict__ bp,
    bf16* __restrict__ Xblk, float* __restrict__ clArr) {
  __shared__ int nbid_l[64];
  __shared__ int n_l[64];
  __shared__ int flat_l[64];
  __shared__ float t_l[64];
  const int tid = threadIdx.x;
  const int side = blockIdx.y;
  const int r0 = blockIdx.x * 64;
  const int* nodes = side ? dstn : srcn;
  if (tid < 64) {
    int rg = r0 + tid;
    int b = rg / 20, k = rg - b * 20;
    int n = nodes[b];
    int flat = n * 20 + k;
    nbid_l[tid] = nbids[flat];
    n_l[tid] = n;
    flat_l[tid] = flat;
    float t = nbt[flat];
    t_l[tid] = t;
    clArr[side * ROWS_NB + rg] = w0p[0] * t + b0p[0];
  }
  __syncthreads();
  const long sliceBase = ((long)(side * 2560 + blockIdx.x)) * 11 * 2048;
  for (int task = tid; task < 64 * 88; task += 256) {
    int r = task / 88; int c = (task - r * 88) * 4;
    float4 v;
    if (c < 128) {
      v = *(const float4*)&memory[(long)nbid_l[r] * ND + c];
    } else if (c < 256) {
      v = *(const float4*)&memory[(long)n_l[r] * ND + (c - 128)];
    } else if (c < 320) {
      v = *(const float4*)&nbe[(long)flat_l[r] * 64 + (c - 256)];
    } else {
      float t = t_l[r];
      float vv[4];
#pragma unroll
      for (int q = 0; q < 4; ++q) {
        int cc = c + q - 320;
        vv[q] = (cc == 0) ? 0.f : sinf(wp[cc - 1] * t + bp[cc - 1]);
      }
      v = make_float4(vv[0], vv[1], vv[2], vv[3]);
    }
    int k0 = c >> 5, c16 = (c & 31) >> 3, off = c & 7;
    int p = r * 4 + (c16 ^ ((r >> 1) & 3));
    long idx = sliceBase + (long)k0 * 2048 + p * 8 + off;
    union { bf16 h[4]; uint2 u; } pk;
    pk.h[0] = (bf16)v.x; pk.h[1] = (bf16)v.y; pk.h[2] = (bf16)v.z; pk.h[3] = (bf16)v.w;
    *(uint2*)&Xblk[idx] = pk.u;
  }
}

// ---------------- fused MLP GEMM + mean ----------------
// grid (4, 2560): x = z = layer*2+side (z-inner => L3 reuse of X slices), y = blk
// block: 256 threads = 4 waves; M=64 rows; M1: wave = 64r x 64c (4x4 tiles);
// M2: wave = 64r x 32c. Staging via global_load_lds, double-buffered.
#define SMEM_STG 0          // M1: 2 x 20480 (X 4KB @0, W1 16KB @4096); M2: 2 x 16384
#define SMEM_HHI 40960      // bf16 [64][136] = 17408
#define SMEM_HLO 58368      // bf16 [64][136] = 17408
#define SMEM_MROW 40960     // f32 [64][136] = 34816 (overlays h planes)
#define SMEM_CL 75776       // f32 [64]
#define SMEM_TOT 76032
__global__ __launch_bounds__(256, 2) void k_mlp(
    const bf16* __restrict__ Xblk, const float* __restrict__ clArr,
    const bf16* __restrict__ W1blk, const bf16* __restrict__ W2blk,
    const float* __restrict__ w320, const float* __restrict__ b1,
    const float* __restrict__ b2, float* __restrict__ nb_out) {
  __shared__ __align__(16) char smem[SMEM_TOT];
  char* stg = smem;
  bf16* hhi = (bf16*)(smem + SMEM_HHI);
  bf16* hlo = (bf16*)(smem + SMEM_HLO);
  float* mrow = (float*)(smem + SMEM_MROW);
  float* cl = (float*)(smem + SMEM_CL);

  const int tid = threadIdx.x;
  const int wid = tid >> 6, lane = tid & 63;
  const int colq = lane & 15, cq = lane >> 4;
  const int cx = cq ^ ((colq >> 1) & 3);
  const int rsub = (lane >> 4) * 4;
  const int z = blockIdx.x, layer = z >> 1, side = z & 1;
  const int blk = blockIdx.y;

  const bf16* Xs = Xblk + ((long)(side * 2560 + blk)) * 11 * 2048;
  const bf16* W1s = W1blk + layer * 11 * 8192;
  const bf16* W2hiS = W2blk + (layer * 2 + 0) * 8 * 4096;
  const bf16* W2loS = W2blk + (layer * 2 + 1) * 8 * 4096;

  if (tid < 64) cl[tid] = clArr[side * ROWS_NB + blk * 64 + tid];

  auto stageM1 = [&](int k0, int buf) {
    char* dst = stg + buf * 20480;
#pragma unroll
    for (int q = 0; q < 5; ++q) {
      int i = wid * 5 + q;
      const bf16* src = (i < 4) ? (Xs + (long)k0 * 2048 + i * 512 + lane * 8)
                                : (W1s + (long)k0 * 8192 + (i - 4) * 512 + lane * 8);
      stage16(src, dst + i * 1024 + lane * 16);
    }
  };
  auto stageM2 = [&](int kg, int buf) {
    char* dst = stg + buf * 16384;
#pragma unroll
    for (int q = 0; q < 4; ++q) {
      int i = wid * 4 + q;
      const bf16* src = ((i < 8) ? W2hiS : W2loS) + (long)kg * 4096 + (i & 7) * 512 + lane * 8;
      stage16(src, dst + i * 1024 + lane * 16);
    }
  };

  int aoff[4], boff[4];
#pragma unroll
  for (int m = 0; m < 4; ++m) aoff[m] = (m * 16 + colq) * 64 + cx * 16;
#pragma unroll
  for (int n = 0; n < 4; ++n) {
    int ng = wid * 64 + n * 16 + colq;
    boff[n] = 4096 + ng * 64 + cx * 16;
  }

  stageM1(0, 0);
  __syncthreads();

  f32x4 acc[4][4];
#pragma unroll
  for (int m = 0; m < 4; ++m)
#pragma unroll
    for (int n = 0; n < 4; ++n) acc[m][n] = (f32x4){0.f, 0.f, 0.f, 0.f};

  for (int k0 = 0; k0 < 11; ++k0) {
    int cur = k0 & 1;
    if (k0 < 10) stageM1(k0 + 1, cur ^ 1);
    const char* base = stg + cur * 20480;
    bf16x8 a[4], b[4];
#pragma unroll
    for (int m = 0; m < 4; ++m) a[m] = *(const bf16x8*)(base + aoff[m]);
#pragma unroll
    for (int n = 0; n < 4; ++n) b[n] = *(const bf16x8*)(base + boff[n]);
#pragma unroll
    for (int m = 0; m < 4; ++m)
#pragma unroll
      for (int n = 0; n < 4; ++n) acc[m][n] = MFMA16(a[m], b[n], acc[m][n]);
    __syncthreads();
  }

  // h = acc + cl*w320 + b1, relu (kept in acc for deferred dump)
  const float* w320l = w320 + layer * 256;
  const float* b1l = b1 + layer * 256;
#pragma unroll
  for (int n = 0; n < 4; ++n) {
    int cg = wid * 64 + n * 16 + colq;
    float wv = w320l[cg], bv = b1l[cg];
#pragma unroll
    for (int m = 0; m < 4; ++m)
#pragma unroll
      for (int i = 0; i < 4; ++i) {
        int r = m * 16 + rsub + i;
        float v = acc[m][n][i] + cl[r] * wv + bv;
        acc[m][n][i] = fmaxf(v, 0.f);
      }
  }

  // first-half dump (cols 0..127) + prefetch W2 slice 0
  stageM2(0, 0);
  if (wid < 2) {
#pragma unroll
    for (int m = 0; m < 4; ++m)
#pragma unroll
      for (int n = 0; n < 4; ++n)
#pragma unroll
        for (int i = 0; i < 4; ++i) {
          int r = m * 16 + rsub + i;
          int cc = (wid & 1) * 64 + n * 16 + colq;
          bf16 hi, lo; split2(acc[m][n][i], hi, lo);
          hhi[r * 136 + cc] = hi;
          hlo[r * 136 + cc] = lo;
        }
  }
  __syncthreads();

  // M2: m = relu(h) @ W2 (hi/lo x hi/lo, 3 products), K accumulated over 2 passes
  f32x4 acc2[4][2];
#pragma unroll
  for (int m = 0; m < 4; ++m)
#pragma unroll
    for (int n = 0; n < 2; ++n) acc2[m][n] = (f32x4){0.f, 0.f, 0.f, 0.f};

  int ahoffB[4], b2off[2];
#pragma unroll
  for (int m = 0; m < 4; ++m) ahoffB[m] = (m * 16 + colq) * 272 + cq * 16;
#pragma unroll
  for (int n = 0; n < 2; ++n) b2off[n] = (wid * 32 + n * 16 + colq) * 64 + cx * 16;

  for (int kg = 0; kg < 8; ++kg) {
    int cur = kg & 1;
    if (kg < 7) stageM2(kg + 1, cur ^ 1);
    const char* wbuf = stg + cur * 16384;
    int kh = kg & 3;
    bf16x8 ahi[4], alo[4], bhi[2], blo[2];
#pragma unroll
    for (int m = 0; m < 4; ++m) {
      ahi[m] = *(const bf16x8*)((char*)hhi + ahoffB[m] + kh * 64);
      alo[m] = *(const bf16x8*)((char*)hlo + ahoffB[m] + kh * 64);
    }
#pragma unroll
    for (int n = 0; n < 2; ++n) {
      bhi[n] = *(const bf16x8*)(wbuf + b2off[n]);
      blo[n] = *(const bf16x8*)(wbuf + 8192 + b2off[n]);
    }
#pragma unroll
    for (int m = 0; m < 4; ++m)
#pragma unroll
      for (int n = 0; n < 2; ++n) {
        acc2[m][n] = MFMA16(ahi[m], bhi[n], acc2[m][n]);
        acc2[m][n] = MFMA16(ahi[m], blo[n], acc2[m][n]);
        acc2[m][n] = MFMA16(alo[m], bhi[n], acc2[m][n]);
      }
    __syncthreads();
    if (kg == 3) {
      // second-half dump (cols 128..255 -> local 0..127)
      if (wid >= 2) {
#pragma unroll
        for (int m = 0; m < 4; ++m)
#pragma unroll
          for (int n = 0; n < 4; ++n)
#pragma unroll
            for (int i = 0; i < 4; ++i) {
              int r = m * 16 + rsub + i;
              int cc = (wid & 1) * 64 + n * 16 + colq;
              bf16 hi, lo; split2(acc[m][n][i], hi, lo);
              hhi[r * 136 + cc] = hi;
              hlo[r * 136 + cc] = lo;
            }
      }
      __syncthreads();
    }
  }

  // finalize m, write to LDS (overlaying h planes), then k-mean + atomics
  const float* b2l = b2 + layer * 128;
#pragma unroll
  for (int n = 0; n < 2; ++n) {
    int cg = wid * 32 + n * 16 + colq;
    float bv = b2l[cg];
#pragma unroll
    for (int m = 0; m < 4; ++m)
#pragma unroll
      for (int i = 0; i < 4; ++i) {
        int r = m * 16 + rsub + i;
        mrow[r * 136 + cg] = (acc2[m][n][i] + bv) * 0.05f;
      }
  }
  __syncthreads();

  {
    int colr = tid & 127, half = tid >> 7;
    int r0g = blk * 64;
    int bf0 = r0g / 20;
    long zbase = (long)z * NB_EV * ND;
    for (int bi = half; bi <= 4; bi += 2) {
      int b = bf0 + bi;
      if (b >= NB_EV) break;
      int rlo = b * 20 - r0g, rhi = rlo + 20;
      rlo = max(rlo, 0); rhi = min(rhi, 64);
      if (rlo >= rhi) continue;
      float s = 0.f;
      for (int r = rlo; r < rhi; ++r) s += mrow[r * 136 + colr];
      atomicAdd(&nb_out[zbase + (long)b * ND + colr], s);
    }
  }
}

// ---------------- fallback: round-1 fused neighbor kernel ----------------
#define XSS 360
#define HSS 264
#define MSS_NB 132
__global__ __launch_bounds__(256) void k_neighbor(
    const int* __restrict__ srcn, const int* __restrict__ dstn,
    const float* __restrict__ memory, const int* __restrict__ nbids,
    const float* __restrict__ nbt, const float* __restrict__ nbe,
    const float* __restrict__ w0p, const float* __restrict__ b0p,
    const float* __restrict__ wp, const float* __restrict__ bp,
    const bf16* __restrict__ W1T, const float* __restrict__ w320, const float* __restrict__ b1,
    const bf16* __restrict__ W2Thi, const bf16* __restrict__ W2Tlo, const float* __restrict__ b2,
    float* __restrict__ nb_out) {
  __shared__ __align__(16) char smem[68864];
  bf16* xs = (bf16*)smem;
  bf16* hhi = (bf16*)smem;
  bf16* hlo = (bf16*)(smem + 33792);
  float* msgs = (float*)smem;
  int* nbid_l = (int*)(smem + 67584);
  int* n_l = nbid_l + 64;
  int* flat_l = n_l + 64;
  float* t_l = (float*)(flat_l + 64);
  float* c_l = t_l + 64;

  const int tid = threadIdx.x;
  const int z = blockIdx.y;
  const int layer = z >> 1, side = z & 1;
  const int r0 = blockIdx.x * 64;
  const int* nodes = side ? dstn : srcn;

  if (tid < 64) {
    int rg = r0 + tid;
    int b = rg / 20, k = rg - b * 20;
    int n = nodes[b];
    int flat = n * 20 + k;
    nbid_l[tid] = nbids[flat];
    n_l[tid] = n;
    flat_l[tid] = flat;
    float t = nbt[flat];
    t_l[tid] = t;
    c_l[tid] = w0p[0] * t + b0p[0];
  }
  __syncthreads();

  for (int task = tid; task < 64 * 88; task += 256) {
    int r = task / 88; int c = (task - r * 88) * 4;
    float4 v;
    if (c < 128) {
      v = *(const float4*)&memory[(long)nbid_l[r] * ND + c];
    } else if (c < 256) {
      v = *(const float4*)&memory[(long)n_l[r] * ND + (c - 128)];
    } else if (c < 320) {
      v = *(const float4*)&nbe[(long)flat_l[r] * 64 + (c - 256)];
    } else {
      float t = t_l[r];
      float vv[4];
#pragma unroll
      for (int q = 0; q < 4; ++q) {
        int cc = c + q - 320;
        vv[q] = (cc == 0) ? 0.f : sinf(wp[cc - 1] * t + bp[cc - 1]);
      }
      v = make_float4(vv[0], vv[1], vv[2], vv[3]);
    }
    union { bf16 h[4]; uint2 u; } pk;
    pk.h[0] = (bf16)v.x; pk.h[1] = (bf16)v.y; pk.h[2] = (bf16)v.z; pk.h[3] = (bf16)v.w;
    *(uint2*)&xs[r * XSS + c] = pk.u;
  }
  __syncthreads();

  const int wid = tid >> 6, lane = tid & 63;
  const int col = lane & 15, ko8 = (lane >> 4) * 8;
  const int rb = wid * 16;
  const int rowA = rb + col;
  const int rbase = rb + (lane >> 4) * 4;
  const bf16* W1Tl = W1T + layer * 90112;

  f32x4 acc[16];
#pragma unroll
  for (int nt = 0; nt < 16; ++nt) acc[nt] = (f32x4){0.f, 0.f, 0.f, 0.f};
#pragma unroll
  for (int k0 = 0; k0 < IN_DIM; k0 += 32) {
    bf16x8 a = *(const bf16x8*)&xs[rowA * XSS + k0 + ko8];
    const bf16* wb = W1Tl + k0 + ko8;
#pragma unroll
    for (int nt = 0; nt < 16; ++nt) {
      bf16x8 bfr = *(const bf16x8*)(wb + (nt * 16 + col) * IN_DIM);
      acc[nt] = MFMA16(a, bfr, acc[nt]);
    }
  }
  __syncthreads();

  const float* b1l = b1 + layer * 256;
  const float* w320l = w320 + layer * 256;
#pragma unroll
  for (int nt = 0; nt < 16; ++nt) {
    int cc = nt * 16 + col;
    float wv = w320l[cc], bv = b1l[cc];
#pragma unroll
    for (int i = 0; i < 4; ++i) {
      int rr = rbase + i;
      float v = acc[nt][i] + c_l[rr] * wv + bv;
      v = fmaxf(v, 0.f);
      bf16 hi, lo; split2(v, hi, lo);
      hhi[rr * HSS + cc] = hi;
      hlo[rr * HSS + cc] = lo;
    }
  }
  __syncthreads();

  const bf16* W2hl = W2Thi + layer * 32768;
  const bf16* W2ll = W2Tlo + layer * 32768;
  f32x4 acc2[8];
#pragma unroll
  for (int nt = 0; nt < 8; ++nt) acc2[nt] = (f32x4){0.f, 0.f, 0.f, 0.f};
#pragma unroll
  for (int k0 = 0; k0 < HID; k0 += 32) {
    bf16x8 ahi = *(const bf16x8*)&hhi[rowA * HSS + k0 + ko8];
    bf16x8 alo = *(const bf16x8*)&hlo[rowA * HSS + k0 + ko8];
#pragma unroll
    for (int nt = 0; nt < 8; ++nt) {
      int n = nt * 16 + col;
      bf16x8 bhi = *(const bf16x8*)(W2hl + n * HID + k0 + ko8);
      bf16x8 blo = *(const bf16x8*)(W2ll + n * HID + k0 + ko8);
      acc2[nt] = MFMA16(ahi, bhi, acc2[nt]);
      acc2[nt] = MFMA16(ahi, blo, acc2[nt]);
      acc2[nt] = MFMA16(alo, bhi, acc2[nt]);
    }
  }
  __syncthreads();

  const float* b2l = b2 + layer * 128;
#pragma unroll
  for (int nt = 0; nt < 8; ++nt) {
    int cc = nt * 16 + col;
    float bv = b2l[cc];
#pragma unroll
    for (int i = 0; i < 4; ++i)
      msgs[(rbase + i) * MSS_NB + cc] = (acc2[nt][i] + bv) * 0.05f;
  }
  __syncthreads();

  {
    int colr = tid & 127, half = tid >> 7;
    int bf0 = r0 / 20;
    for (int bi = half; bi <= 4; bi += 2) {
      int b = bf0 + bi;
      if (b >= NB_EV) break;
      int rlo = b * 20 - r0, rhi = rlo + 20;
      rlo = max(rlo, 0); rhi = min(rhi, 64);
      if (rlo >= rhi) continue;
      float s = 0.f;
      for (int r = rlo; r < rhi; ++r) s += msgs[r * MSS_NB + colr];
      atomicAdd(&nb_out[((long)((layer * 2 + side) * NB_EV + b)) * ND + colr], s);
    }
  }
}

// ---------------- event chain: MLP + GRU (one launch per layer) ----------------
#define MSS_EV 136
__global__ __launch_bounds__(256) void k_event(
    int layer, const float* __restrict__ embA_in, const float* __restrict__ embB_in,
    float* __restrict__ outA, int ostrideA, float* __restrict__ outB, int ostrideB,
    const float* __restrict__ time_emb, const float* __restrict__ edge_enc,
    const bf16* __restrict__ W1T, const float* __restrict__ w320, const float* __restrict__ b1,
    const bf16* __restrict__ W2Thi, const bf16* __restrict__ W2Tlo, const float* __restrict__ b2,
    const float* __restrict__ nb_out,
    const bf16* __restrict__ wihhi, const bf16* __restrict__ wihlo,
    const bf16* __restrict__ whhhi, const bf16* __restrict__ whhlo,
    const float* __restrict__ bih, const float* __restrict__ bhh) {
  __shared__ __align__(16) char smem[102656];
  bf16* xs = (bf16*)smem;
  bf16* hhi = (bf16*)smem;
  bf16* hlo = (bf16*)(smem + 33792);
  bf16* mhi = (bf16*)smem;
  bf16* mlo = (bf16*)(smem + 17408);
  bf16* ghi = (bf16*)(smem + 67584);
  bf16* glo = (bf16*)(smem + 67584 + 17408);
  float* c_l = (float*)(smem + 102400);

  const int tid = threadIdx.x;
  const int r0 = blockIdx.x * 64;
  const int side = r0 >> 13;
  const int b0r = r0 & (NB_EV - 1);
  const float* ea = side ? embB_in : embA_in;
  const float* eb = side ? embA_in : embB_in;

  if (tid < 64) c_l[tid] = time_emb[(b0r + tid) * 32];

  for (int task = tid; task < 64 * 88; task += 256) {
    int r = task / 88; int c = (task - r * 88) * 4;
    int b = b0r + r;
    float4 v;
    if (c < 128) {
      v = *(const float4*)&ea[(long)b * ND + c];
      bf16 h0, l0, h1, l1, h2, l2, h3, l3;
      split2(v.x, h0, l0); split2(v.y, h1, l1); split2(v.z, h2, l2); split2(v.w, h3, l3);
      ghi[r * MSS_EV + c + 0] = h0; glo[r * MSS_EV + c + 0] = l0;
      ghi[r * MSS_EV + c + 1] = h1; glo[r * MSS_EV + c + 1] = l1;
      ghi[r * MSS_EV + c + 2] = h2; glo[r * MSS_EV + c + 2] = l2;
      ghi[r * MSS_EV + c + 3] = h3; glo[r * MSS_EV + c + 3] = l3;
    } else if (c < 256) {
      v = *(const float4*)&eb[(long)b * ND + (c - 128)];
    } else if (c < 320) {
      v = *(const float4*)&edge_enc[(long)b * 64 + (c - 256)];
    } else {
      float vv[4];
#pragma unroll
      for (int q = 0; q < 4; ++q) {
        int cc = c + q - 320;
        vv[q] = (cc == 0) ? 0.f : time_emb[b * 32 + cc];
      }
      v = make_float4(vv[0], vv[1], vv[2], vv[3]);
    }
    union { bf16 h[4]; uint2 u; } pk;
    pk.h[0] = (bf16)v.x; pk.h[1] = (bf16)v.y; pk.h[2] = (bf16)v.z; pk.h[3] = (bf16)v.w;
    *(uint2*)&xs[r * XSS + c] = pk.u;
  }
  __syncthreads();

  const int wid = tid >> 6, lane = tid & 63;
  const int col = lane & 15, ko8 = (lane >> 4) * 8;
  const int rb = wid * 16;
  const int rowA = rb + col;
  const int rbase = rb + (lane >> 4) * 4;
  const bf16* W1Tl = W1T + layer * 90112;

  f32x4 acc[16];
#pragma unroll
  for (int nt = 0; nt < 16; ++nt) acc[nt] = (f32x4){0.f, 0.f, 0.f, 0.f};
#pragma unroll
  for (int k0 = 0; k0 < IN_DIM; k0 += 32) {
    bf16x8 a = *(const bf16x8*)&xs[rowA * XSS + k0 + ko8];
    const bf16* wb = W1Tl + k0 + ko8;
#pragma unroll
    for (int nt = 0; nt < 16; ++nt) {
      bf16x8 bfr = *(const bf16x8*)(wb + (nt * 16 + col) * IN_DIM);
      acc[nt] = MFMA16(a, bfr, acc[nt]);
    }
  }
  __syncthreads();

  const float* b1l = b1 + layer * 256;
  const float* w320l = w320 + layer * 256;
#pragma unroll
  for (int nt = 0; nt < 16; ++nt) {
    int cc = nt * 16 + col;
    float wv = w320l[cc], bv = b1l[cc];
#pragma unroll
    for (int i = 0; i < 4; ++i) {
      int rr = rbase + i;
      float v = acc[nt][i] + c_l[rr] * wv + bv;
      v = fmaxf(v, 0.f);
      bf16 hi, lo; split2(v, hi, lo);
      hhi[rr * HSS + cc] = hi;
      hlo[rr * HSS + cc] = lo;
    }
  }
  __syncthreads();

  const bf16* W2hl = W2Thi + layer * 32768;
  const bf16* W2ll = W2Tlo + layer * 32768;
  f32x4 acc2[8];
#pragma unroll
  for (int nt = 0; nt < 8; ++nt) acc2[nt] = (f32x4){0.f, 0.f, 0.f, 0.f};
#pragma unroll
  for (int k0 = 0; k0 < HID; k0 += 32) {
    bf16x8 ahi = *(const bf16x8*)&hhi[rowA * HSS + k0 + ko8];
    bf16x8 alo = *(const bf16x8*)&hlo[rowA * HSS + k0 + ko8];
#pragma unroll
    for (int nt = 0; nt < 8; ++nt) {
      int n = nt * 16 + col;
      bf16x8 bhi = *(const bf16x8*)(W2hl + n * HID + k0 + ko8);
      bf16x8 blo = *(const bf16x8*)(W2ll + n * HID + k0 + ko8);
      acc2[nt] = MFMA16(ahi, bhi, acc2[nt]);
      acc2[nt] = MFMA16(ahi, blo, acc2[nt]);
      acc2[nt] = MFMA16(alo, bhi, acc2[nt]);
    }
  }
  __syncthreads();

  const float* b2l = b2 + layer * 128;
  const float* nbl = nb_out + ((long)(layer * 2 + side)) * NB_EV * ND;
#pragma unroll
  for (int nt = 0; nt < 8; ++nt) {
    int cc = nt * 16 + col;
    float bv = b2l[cc];
#pragma unroll
    for (int i = 0; i < 4; ++i) {
      int rr = rbase + i;
      float mval = acc2[nt][i] + bv + nbl[(long)(b0r + rr) * ND + cc];
      bf16 hi, lo; split2(mval, hi, lo);
      mhi[rr * MSS_EV + cc] = hi;
      mlo[rr * MSS_EV + cc] = lo;
    }
  }
  __syncthreads();

  float* outP = side ? outB : outA;
  const int ostride = side ? ostrideB : ostrideA;
  for (int jt = 0; jt < 8; ++jt) {
    f32x4 gx[3], gh[3];
#pragma unroll
    for (int g = 0; g < 3; ++g) {
      gx[g] = (f32x4){0.f, 0.f, 0.f, 0.f};
      gh[g] = (f32x4){0.f, 0.f, 0.f, 0.f};
    }
#pragma unroll
    for (int k0 = 0; k0 < ND; k0 += 32) {
      bf16x8 amh = *(const bf16x8*)&mhi[rowA * MSS_EV + k0 + ko8];
      bf16x8 aml = *(const bf16x8*)&mlo[rowA * MSS_EV + k0 + ko8];
      bf16x8 ahh = *(const bf16x8*)&ghi[rowA * MSS_EV + k0 + ko8];
      bf16x8 ahl = *(const bf16x8*)&glo[rowA * MSS_EV + k0 + ko8];
#pragma unroll
      for (int g = 0; g < 3; ++g) {
        int n = g * 128 + jt * 16 + col;
        bf16x8 bh = *(const bf16x8*)(wihhi + n * ND + k0 + ko8);
        bf16x8 bl = *(const bf16x8*)(wihlo + n * ND + k0 + ko8);
        gx[g] = MFMA16(amh, bh, gx[g]);
        gx[g] = MFMA16(aml, bh, gx[g]);
        gx[g] = MFMA16(amh, bl, gx[g]);
        bf16x8 ch = *(const bf16x8*)(whhhi + n * ND + k0 + ko8);
        bf16x8 cl2 = *(const bf16x8*)(whhlo + n * ND + k0 + ko8);
        gh[g] = MFMA16(ahh, ch, gh[g]);
        gh[g] = MFMA16(ahl, ch, gh[g]);
        gh[g] = MFMA16(ahh, cl2, gh[g]);
      }
    }
    int j = jt * 16 + col;
    float bihr = bih[j], bihz = bih[128 + j], bihn = bih[256 + j];
    float bhhr = bhh[j], bhhz = bhh[128 + j], bhhn = bhh[256 + j];
#pragma unroll
    for (int i = 0; i < 4; ++i) {
      int rr = rbase + i;
      float rx = gx[0][i] + bihr, zx = gx[1][i] + bihz, nx = gx[2][i] + bihn;
      float rh = gh[0][i] + bhhr, zh = gh[1][i] + bhhz, nh = gh[2][i] + bhhn;
      float r = 1.f / (1.f + expf(-(rx + rh)));
      float zz = 1.f / (1.f + expf(-(zx + zh)));
      float n = tanhf(nx + r * nh);
      float hval = (float)ghi[rr * MSS_EV + j] + (float)glo[rr * MSS_EV + j];
      outP[(long)(b0r + rr) * ostride + j] = (1.f - zz) * n + zz * hval;
    }
  }
}

// ---------------- launch ----------------
extern "C" void kernel_launch(void* const* d_in, const int* in_sizes, int n_in,
                              void* d_out, int out_size, void* d_ws, size_t ws_size,
                              hipStream_t stream) {
  const int* srcn = (const int*)d_in[0];
  const int* dstn = (const int*)d_in[1];
  const float* edge_attrs = (const float*)d_in[2];
  const float* timestamps = (const float*)d_in[3];
  const float* memory = (const float*)d_in[4];
  const int* neighbor_ids = (const int*)d_in[5];
  const float* neighbor_times = (const float*)d_in[6];
  const float* neighbor_edge_attrs = (const float*)d_in[7];
  const float* t2v_w0 = (const float*)d_in[8];
  const float* t2v_b0 = (const float*)d_in[9];
  const float* t2v_w = (const float*)d_in[10];
  const float* t2v_b = (const float*)d_in[11];
  const float* enc_W = (const float*)d_in[12];
  const float* enc_b = (const float*)d_in[13];
  const float* mlp_W1 = (const float*)d_in[14];
  const float* mlp_b1 = (const float*)d_in[15];
  const float* mlp_W2 = (const float*)d_in[16];
  const float* mlp_b2 = (const float*)d_in[17];
  const float* gru_w_ih = (const float*)d_in[18];
  const float* gru_w_hh = (const float*)d_in[19];
  const float* gru_b_ih = (const float*)d_in[20];
  const float* gru_b_hh = (const float*)d_in[21];

  char* ws = (char*)d_ws;
  size_t off = 0;
  auto alloc = [&](size_t bytes) { size_t o = off; off += (bytes + 255) & ~(size_t)255; return o; };
  bf16* W1T = (bf16*)(ws + alloc(2 * 256 * 352 * 2));
  bf16* W2Thi = (bf16*)(ws + alloc(2 * 128 * 256 * 2));
  bf16* W2Tlo = (bf16*)(ws + alloc(2 * 128 * 256 * 2));
  bf16* wihhi = (bf16*)(ws + alloc(384 * 128 * 2));
  bf16* wihlo = (bf16*)(ws + alloc(384 * 128 * 2));
  bf16* whhhi = (bf16*)(ws + alloc(384 * 128 * 2));
  bf16* whhlo = (bf16*)(ws + alloc(384 * 128 * 2));
  float* w320 = (float*)(ws + alloc(512 * 4));
  float* time_emb = (float*)(ws + alloc((size_t)NB_EV * 32 * 4));
  float* edge_enc = (float*)(ws + alloc((size_t)NB_EV * 64 * 4));
  float* embA0 = (float*)(ws + alloc((size_t)NB_EV * ND * 4));
  float* embB0 = (float*)(ws + alloc((size_t)NB_EV * ND * 4));
  float* embA1 = (float*)(ws + alloc((size_t)NB_EV * ND * 4));
  float* embB1 = (float*)(ws + alloc((size_t)NB_EV * ND * 4));
  float* nb_out = (float*)(ws + alloc((size_t)4 * NB_EV * ND * 4));
  // fast-path arrays
  bf16* W1blk = (bf16*)(ws + alloc((size_t)2 * 11 * 8192 * 2));
  bf16* W2blk = (bf16*)(ws + alloc((size_t)2 * 2 * 8 * 4096 * 2));
  float* clArr = (float*)(ws + alloc((size_t)2 * ROWS_NB * 4));
  bf16* Xblk = (bf16*)(ws + alloc((size_t)2 * ROWS_NB * IN_DIM * 2));
  const bool fast = (off <= ws_size);

  k_prep_weights<<<512, 256, 0, stream>>>(mlp_W1, mlp_W2, gru_w_ih, gru_w_hh,
                                          W1T, W2Thi, W2Tlo, wihhi, wihlo, whhhi, whhlo, w320,
                                          W1blk, W2blk, fast ? 1 : 0);
  k_prep_misc<<<2048, 256, 0, stream>>>(timestamps, t2v_w0, t2v_b0, t2v_w, t2v_b,
                                        srcn, dstn, memory, time_emb, embA0, embB0, nb_out);
  k_edge<<<NB_EV, 64, 0, stream>>>(edge_attrs, enc_W, enc_b, edge_enc);

  if (fast) {
    k_build_x<<<dim3(2560, 2, 1), 256, 0, stream>>>(
        srcn, dstn, memory, neighbor_ids, neighbor_times, neighbor_edge_attrs,
        t2v_w0, t2v_b0, t2v_w, t2v_b, Xblk, clArr);
    k_mlp<<<dim3(4, 2560, 1), 256, 0, stream>>>(
        Xblk, clArr, W1blk, W2blk, w320, mlp_b1, mlp_b2, nb_out);
  } else {
    k_neighbor<<<dim3(ROWS_NB / 64, 4, 1), 256, 0, stream>>>(
        srcn, dstn, memory, neighbor_ids, neighbor_times, neighbor_edge_attrs,
        t2v_w0, t2v_b0, t2v_w, t2v_b, W1T, w320, mlp_b1, W2Thi, W2Tlo, mlp_b2, nb_out);
  }

  k_event<<<2 * NB_EV / 64, 256, 0, stream>>>(
      0, embA0, embB0, embA1, ND, embB1, ND, time_emb, edge_enc,
      W1T, w320, mlp_b1, W2Thi, W2Tlo, mlp_b2, nb_out,
      wihhi, wihlo, whhhi, whhlo, gru_b_ih, gru_b_hh);

  float* outf = (float*)d_out;
  k_event<<<2 * NB_EV / 64, 256, 0, stream>>>(
      1, embA1, embB1, outf, 2 * ND, outf + ND, 2 * ND, time_emb, edge_enc,
      W1T, w320, mlp_b1, W2Thi, W2Tlo, mlp_b2, nb_out,
      wihhi, wihlo, whhhi, whhlo, gru_b_ih, gru_b_hh);
}

// Round 4
// 822.338 us; speedup vs baseline: 2.9012x; 1.1162x over previous
//
#include <hip/hip_runtime.h>
#include <math.h>

// TemporalGraphTower on MI355X (gfx950) — round 4.
// Round-3 design (register-direct B-frags from blocked L2-hot layouts, X
// gathered once into LDS, both layers fused) with the h-exchange fixed:
// h (256 cols) is exchanged through LDS in TWO 128-col half-planes
// (stride 136), dumped by wave pairs, with split-K M2 — round-2's proven
// scheme. Round 3's single 136-stride full-width plane corrupted rows.

typedef __bf16 bf16;
typedef __bf16 bf16x8 __attribute__((ext_vector_type(8)));
typedef float f32x4 __attribute__((ext_vector_type(4)));

#define MFMA16(a, b, c) __builtin_amdgcn_mfma_f32_16x16x32_bf16((a), (b), (c), 0, 0, 0)

__device__ __forceinline__ void split2(float v, bf16& hi, bf16& lo) {
  hi = (bf16)v;
  lo = (bf16)(v - (float)hi);
}

#define NB_EV 8192
#define ROWS_NB (NB_EV * 20)   // 163840
#define IN_DIM 352
#define HID 256
#define ND 128

// ---------------- prep: blocked weight layouts (all bf16 / hi-lo split) ----
// W1blk  [2 l][11 k0][256 n][32 k]          (B-frag = 1KB contiguous)
// W2blk  [2 l][2 plane][8 kg][128 n][32 k]
// wihblk/whhblk [2 plane][4 kg][384 n][32 k]
// w320 f32 [2][256] — exact fp32 rank-1 fix for the big time column
__global__ void k_prep_weights(const float* __restrict__ W1, const float* __restrict__ W2,
                               const float* __restrict__ wih, const float* __restrict__ whh,
                               bf16* __restrict__ W1blk, bf16* __restrict__ W2blk,
                               bf16* __restrict__ wihblk, bf16* __restrict__ whhblk,
                               float* __restrict__ w320) {
  const int NW1 = 2 * 11 * 256 * 32;   // 180224
  const int NW2 = 2 * 2 * 8 * 128 * 32; // 131072
  const int NG = 2 * 4 * 384 * 32;     // 98304
  int total = NW1 + NW2 + NG + NG + 512;
  for (int i = blockIdx.x * blockDim.x + threadIdx.x; i < total; i += gridDim.x * blockDim.x) {
    int j = i;
    if (j < NW1) {
      int l = j / 90112, r = j - l * 90112;
      int k0 = r / 8192, r2 = r & 8191;
      int n = r2 >> 5, ko = r2 & 31, k = k0 * 32 + ko;
      W1blk[j] = (bf16)W1[(l * 352 + k) * 256 + n];
    } else if ((j -= NW1) < NW2) {
      int l = j >> 16, r = j & 65535;
      int plane = r >> 15, r2 = r & 32767;
      int kg = r2 >> 12, r3 = r2 & 4095;
      int n = r3 >> 5, ko = r3 & 31, k = kg * 32 + ko;
      bf16 hi, lo; split2(W2[(l * 256 + k) * 128 + n], hi, lo);
      W2blk[j] = plane ? lo : hi;
    } else if ((j -= NW2) < NG) {
      int plane = j / 49152, r = j - plane * 49152;
      int kg = r / 12288, r2 = r - kg * 12288;
      int n = r2 >> 5, ko = r2 & 31, k = kg * 32 + ko;
      bf16 hi, lo; split2(wih[n * 128 + k], hi, lo);
      wihblk[j] = plane ? lo : hi;
    } else if ((j -= NG) < NG) {
      int plane = j / 49152, r = j - plane * 49152;
      int kg = r / 12288, r2 = r - kg * 12288;
      int n = r2 >> 5, ko = r2 & 31, k = kg * 32 + ko;
      bf16 hi, lo; split2(whh[n * 128 + k], hi, lo);
      whhblk[j] = plane ? lo : hi;
    } else {
      j -= NG;
      int l = j >> 8, n = j & 255;
      w320[j] = W1[(l * 352 + 320) * 256 + n];
    }
  }
}

// time2vec table [B][32], initial embedding gathers, zero nb accumulators
__global__ void k_prep_misc(const float* __restrict__ ts, const float* __restrict__ w0,
                            const float* __restrict__ b0, const float* __restrict__ w,
                            const float* __restrict__ bb,
                            const int* __restrict__ srcn, const int* __restrict__ dstn,
                            const float* __restrict__ memory,
                            float* __restrict__ time_emb, float* __restrict__ embA0,
                            float* __restrict__ embB0, float* __restrict__ nb_out) {
  const int N1 = NB_EV * 32, N2 = NB_EV * ND, N3 = 4 * NB_EV * ND;
  int total = N1 + N2 + N3;
  float w0v = w0[0], b0v = b0[0];
  for (int i = blockIdx.x * blockDim.x + threadIdx.x; i < total; i += gridDim.x * blockDim.x) {
    int j = i;
    if (j < N1) {
      int b = j >> 5, c = j & 31;
      float t = ts[b];
      time_emb[j] = (c == 0) ? (w0v * t + b0v) : sinf(w[c - 1] * t + bb[c - 1]);
    } else if ((j -= N1) < N2) {
      int b = j >> 7, c = j & 127;
      embA0[j] = memory[(long)srcn[b] * ND + c];
      embB0[j] = memory[(long)dstn[b] * ND + c];
    } else {
      nb_out[j - N2] = 0.f;
    }
  }
}

// edge_enc[b][j] = sum_k edge_attrs[b][k]*enc_W[k][j] + enc_b[j]
__global__ void k_edge(const float* __restrict__ ea, const float* __restrict__ encW,
                       const float* __restrict__ encb, float* __restrict__ out) {
  __shared__ float row[64];
  int b = blockIdx.x, j = threadIdx.x;
  row[j] = ea[b * 64 + j];
  __syncthreads();
  float s = encb[j];
#pragma unroll
  for (int k = 0; k < 64; ++k) s += row[k] * encW[k * 64 + j];
  out[b * 64 + j] = s;
}

// ---------------- fused neighbor: gather + 2x(M1,M2) + mean ----------------
// grid (2560, 2): x = 64-row tile, y = side. 256 threads = 4 waves; wave owns
// a 64-col strip of M1 (32-col of M2). A-frags LDS, B-frags global->reg.
// h exchange: two 128-col half-planes (stride 136), split-K M2.
#define XSS 360        // xs stride (elems); 720B rows -> 2-way-free banks
#define HSS 136        // h half-plane / m-plane stride (elems)
#define MSS 132        // mrow stride (f32)
#define L_H 46080      // hhi @46080, hlo @63488 ; mrow overlays @46080
#define L_CL 80896
#define L_TOT 81152
__global__ __launch_bounds__(256, 2) void k_nbr(
    const int* __restrict__ srcn, const int* __restrict__ dstn,
    const float* __restrict__ memory, const int* __restrict__ nbids,
    const float* __restrict__ nbt, const float* __restrict__ nbe,
    const float* __restrict__ w0p, const float* __restrict__ b0p,
    const float* __restrict__ wp, const float* __restrict__ bp,
    const bf16* __restrict__ W1blk, const bf16* __restrict__ W2blk,
    const float* __restrict__ w320, const float* __restrict__ b1,
    const float* __restrict__ b2, float* __restrict__ nb_out) {
  __shared__ __align__(16) char smem[L_TOT];
  bf16* xs = (bf16*)(smem);
  bf16* hhi = (bf16*)(smem + L_H);
  bf16* hlo = (bf16*)(smem + L_H + 17408);
  float* mrow = (float*)(smem + L_H);
  float* cl = (float*)(smem + L_CL);
  // gather temps live in the (not yet used) h region
  int* nbid_l = (int*)(smem + L_H);
  int* n_l = nbid_l + 64;
  int* flat_l = n_l + 64;
  float* t_l = (float*)(flat_l + 64);

  const int tid = threadIdx.x;
  const int side = blockIdx.y;
  const int r0 = blockIdx.x * 64;
  const int* nodes = side ? dstn : srcn;

  if (tid < 64) {
    int rg = r0 + tid;
    int b = rg / 20, k = rg - b * 20;
    int n = nodes[b];
    int flat = n * 20 + k;
    nbid_l[tid] = nbids[flat];
    n_l[tid] = n;
    flat_l[tid] = flat;
    float t = nbt[flat];
    t_l[tid] = t;
    cl[tid] = w0p[0] * t + b0p[0];
  }
  __syncthreads();

  // build x tile into LDS: [nb_emb(128) | node_mem(128) | nb_e(64) | t2v(32, col0=0)]
  for (int task = tid; task < 64 * 88; task += 256) {
    int r = task / 88; int c = (task - r * 88) * 4;
    float4 v;
    if (c < 128) {
      v = *(const float4*)&memory[(long)nbid_l[r] * ND + c];
    } else if (c < 256) {
      v = *(const float4*)&memory[(long)n_l[r] * ND + (c - 128)];
    } else if (c < 320) {
      v = *(const float4*)&nbe[(long)flat_l[r] * 64 + (c - 256)];
    } else {
      float t = t_l[r];
      float vv[4];
#pragma unroll
      for (int q = 0; q < 4; ++q) {
        int cc = c + q - 320;
        vv[q] = (cc == 0) ? 0.f : sinf(wp[cc - 1] * t + bp[cc - 1]);
      }
      v = make_float4(vv[0], vv[1], vv[2], vv[3]);
    }
    union { bf16 h[4]; uint2 u; } pk;
    pk.h[0] = (bf16)v.x; pk.h[1] = (bf16)v.y; pk.h[2] = (bf16)v.z; pk.h[3] = (bf16)v.w;
    *(uint2*)&xs[r * XSS + c] = pk.u;
  }
  __syncthreads();

  const int wid = tid >> 6, lane = tid & 63;
  const int colq = lane & 15, cq = lane >> 4;
  const int rsub = cq * 4;

  for (int layer = 0; layer < 2; ++layer) {
    // ---- M1: h = x @ W1 ; A from LDS, B from global (blocked, 1KB/wave-load)
    const bf16* W1l = W1blk + layer * 90112 + (wid * 64 + colq) * 32 + cq * 8;
    const bf16* xsl = xs + colq * XSS + cq * 8;
    f32x4 acc[4][4];
#pragma unroll
    for (int m = 0; m < 4; ++m)
#pragma unroll
      for (int n = 0; n < 4; ++n) acc[m][n] = (f32x4){0.f, 0.f, 0.f, 0.f};
#pragma unroll
    for (int k0 = 0; k0 < 11; ++k0) {
      bf16x8 a[4], b[4];
#pragma unroll
      for (int m = 0; m < 4; ++m) a[m] = *(const bf16x8*)(xsl + m * 16 * XSS + k0 * 32);
#pragma unroll
      for (int n = 0; n < 4; ++n) b[n] = *(const bf16x8*)(W1l + k0 * 8192 + n * 512);
#pragma unroll
      for (int m = 0; m < 4; ++m)
#pragma unroll
        for (int n = 0; n < 4; ++n) acc[m][n] = MFMA16(a[m], b[n], acc[m][n]);
    }

    // rank-1 time fix + bias + relu, kept in acc (wave's 64-col strip)
    const float* w320l = w320 + layer * 256;
    const float* b1l = b1 + layer * 256;
#pragma unroll
    for (int n = 0; n < 4; ++n) {
      int cg = wid * 64 + n * 16 + colq;
      float wv = w320l[cg], bv = b1l[cg];
#pragma unroll
      for (int m = 0; m < 4; ++m)
#pragma unroll
        for (int i = 0; i < 4; ++i) {
          int r = m * 16 + rsub + i;
          acc[m][n][i] = fmaxf(acc[m][n][i] + cl[r] * wv + bv, 0.f);
        }
    }

    // half1 dump (cols 0..127) by waves 0,1
    if (wid < 2) {
#pragma unroll
      for (int m = 0; m < 4; ++m)
#pragma unroll
        for (int n = 0; n < 4; ++n)
#pragma unroll
          for (int i = 0; i < 4; ++i) {
            int r = m * 16 + rsub + i;
            int cc = wid * 64 + n * 16 + colq;
            bf16 hi, lo; split2(acc[m][n][i], hi, lo);
            hhi[r * HSS + cc] = hi;
            hlo[r * HSS + cc] = lo;
          }
    }
    __syncthreads();

    // ---- M2 split-K: m = relu(h) @ W2 (hi/lo x hi/lo, 3 products)
    const bf16* W2h = W2blk + layer * 65536 + (wid * 32 + colq) * 32 + cq * 8;
    const bf16* W2l = W2h + 32768;
    const bf16* hhil = hhi + colq * HSS + cq * 8;
    const bf16* hlol = hlo + colq * HSS + cq * 8;
    f32x4 acc2[4][2];
#pragma unroll
    for (int m = 0; m < 4; ++m)
#pragma unroll
      for (int n = 0; n < 2; ++n) acc2[m][n] = (f32x4){0.f, 0.f, 0.f, 0.f};
#pragma unroll
    for (int kg = 0; kg < 8; ++kg) {
      if (kg == 4) {
        __syncthreads();  // half1 reads done
        if (wid >= 2) {   // half2 dump (cols 128..255 -> local 0..127)
#pragma unroll
          for (int m = 0; m < 4; ++m)
#pragma unroll
            for (int n = 0; n < 4; ++n)
#pragma unroll
              for (int i = 0; i < 4; ++i) {
                int r = m * 16 + rsub + i;
                int cc = (wid & 1) * 64 + n * 16 + colq;
                bf16 hi, lo; split2(acc[m][n][i], hi, lo);
                hhi[r * HSS + cc] = hi;
                hlo[r * HSS + cc] = lo;
              }
        }
        __syncthreads();
      }
      int lk = (kg & 3) * 32;
      bf16x8 ahi[4], alo[4], bhi[2], blo[2];
#pragma unroll
      for (int m = 0; m < 4; ++m) {
        ahi[m] = *(const bf16x8*)(hhil + m * 16 * HSS + lk);
        alo[m] = *(const bf16x8*)(hlol + m * 16 * HSS + lk);
      }
#pragma unroll
      for (int n = 0; n < 2; ++n) {
        bhi[n] = *(const bf16x8*)(W2h + kg * 4096 + n * 512);
        blo[n] = *(const bf16x8*)(W2l + kg * 4096 + n * 512);
      }
#pragma unroll
      for (int m = 0; m < 4; ++m)
#pragma unroll
        for (int n = 0; n < 2; ++n) {
          acc2[m][n] = MFMA16(ahi[m], bhi[n], acc2[m][n]);
          acc2[m][n] = MFMA16(ahi[m], blo[n], acc2[m][n]);
          acc2[m][n] = MFMA16(alo[m], bhi[n], acc2[m][n]);
        }
    }
    __syncthreads();  // h dead -> mrow overlay

    const float* b2l = b2 + layer * 128;
#pragma unroll
    for (int n = 0; n < 2; ++n) {
      int cg = wid * 32 + n * 16 + colq;
      float bv = b2l[cg];
#pragma unroll
      for (int m = 0; m < 4; ++m)
#pragma unroll
        for (int i = 0; i < 4; ++i)
          mrow[(m * 16 + rsub + i) * MSS + cg] = (acc2[m][n][i] + bv) * 0.05f;
    }
    __syncthreads();

    // mean over k within tile, atomic-accumulate per event
    {
      int colr = tid & 127, half = tid >> 7;
      int bf0 = r0 / 20;
      long zbase = (long)(layer * 2 + side) * NB_EV * ND;
      for (int bi = half; bi <= 4; bi += 2) {
        int b = bf0 + bi;
        if (b >= NB_EV) break;
        int rlo = b * 20 - r0, rhi = rlo + 20;
        rlo = max(rlo, 0); rhi = min(rhi, 64);
        if (rlo >= rhi) continue;
        float s = 0.f;
        for (int r = rlo; r < rhi; ++r) s += mrow[r * MSS + colr];
        atomicAdd(&nb_out[zbase + (long)b * ND + colr], s);
      }
    }
    __syncthreads();  // mrow dead before next layer's h dump
  }
}

// ---------------- event chain: MLP + GRU (one launch per layer) ----------------
// grid 256 (2 sides x 128 tiles), 256 threads. Same register-direct B-frags,
// same split-K h exchange. xs region reused for h halves then m planes.
#define E_G 46080      // ghi @46080, glo @63488 (persist)
#define E_CL 80896
#define E_TOT 81152
__global__ __launch_bounds__(256, 1) void k_event(
    int layer, const float* __restrict__ embA_in, const float* __restrict__ embB_in,
    float* __restrict__ outA, int ostrideA, float* __restrict__ outB, int ostrideB,
    const float* __restrict__ time_emb, const float* __restrict__ edge_enc,
    const bf16* __restrict__ W1blk, const bf16* __restrict__ W2blk,
    const float* __restrict__ w320, const float* __restrict__ b1,
    const float* __restrict__ b2, const float* __restrict__ nb_out,
    const bf16* __restrict__ wihblk, const bf16* __restrict__ whhblk,
    const float* __restrict__ bih, const float* __restrict__ bhh) {
  __shared__ __align__(16) char smem[E_TOT];
  bf16* xs = (bf16*)(smem);
  bf16* hhi = (bf16*)(smem);                 // half-plane, overlays xs after M1
  bf16* hlo = (bf16*)(smem + 17408);
  bf16* mhi = (bf16*)(smem);                 // overlays h after M2
  bf16* mlo = (bf16*)(smem + 17408);
  bf16* ghi = (bf16*)(smem + E_G);
  bf16* glo = (bf16*)(smem + E_G + 17408);
  float* cl = (float*)(smem + E_CL);

  const int tid = threadIdx.x;
  const int r0 = blockIdx.x * 64;
  const int side = r0 >> 13;
  const int b0r = r0 & (NB_EV - 1);
  const float* ea = side ? embB_in : embA_in;   // own embedding (GRU h)
  const float* eb = side ? embA_in : embB_in;

  if (tid < 64) cl[tid] = time_emb[(b0r + tid) * 32];

  for (int task = tid; task < 64 * 88; task += 256) {
    int r = task / 88; int c = (task - r * 88) * 4;
    int b = b0r + r;
    float4 v;
    if (c < 128) {
      v = *(const float4*)&ea[(long)b * ND + c];
      bf16 h0, l0, h1, l1, h2, l2, h3, l3;
      split2(v.x, h0, l0); split2(v.y, h1, l1); split2(v.z, h2, l2); split2(v.w, h3, l3);
      ghi[r * HSS + c + 0] = h0; glo[r * HSS + c + 0] = l0;
      ghi[r * HSS + c + 1] = h1; glo[r * HSS + c + 1] = l1;
      ghi[r * HSS + c + 2] = h2; glo[r * HSS + c + 2] = l2;
      ghi[r * HSS + c + 3] = h3; glo[r * HSS + c + 3] = l3;
    } else if (c < 256) {
      v = *(const float4*)&eb[(long)b * ND + (c - 128)];
    } else if (c < 320) {
      v = *(const float4*)&edge_enc[(long)b * 64 + (c - 256)];
    } else {
      float vv[4];
#pragma unroll
      for (int q = 0; q < 4; ++q) {
        int cc = c + q - 320;
        vv[q] = (cc == 0) ? 0.f : time_emb[b * 32 + cc];
      }
      v = make_float4(vv[0], vv[1], vv[2], vv[3]);
    }
    union { bf16 h[4]; uint2 u; } pk;
    pk.h[0] = (bf16)v.x; pk.h[1] = (bf16)v.y; pk.h[2] = (bf16)v.z; pk.h[3] = (bf16)v.w;
    *(uint2*)&xs[r * XSS + c] = pk.u;
  }
  __syncthreads();

  const int wid = tid >> 6, lane = tid & 63;
  const int colq = lane & 15, cq = lane >> 4;
  const int rsub = cq * 4;

  // ---- M1
  const bf16* W1l = W1blk + layer * 90112 + (wid * 64 + colq) * 32 + cq * 8;
  const bf16* xsl = xs + colq * XSS + cq * 8;
  f32x4 acc[4][4];
#pragma unroll
  for (int m = 0; m < 4; ++m)
#pragma unroll
    for (int n = 0; n < 4; ++n) acc[m][n] = (f32x4){0.f, 0.f, 0.f, 0.f};
#pragma unroll
  for (int k0 = 0; k0 < 11; ++k0) {
    bf16x8 a[4], b[4];
#pragma unroll
    for (int m = 0; m < 4; ++m) a[m] = *(const bf16x8*)(xsl + m * 16 * XSS + k0 * 32);
#pragma unroll
    for (int n = 0; n < 4; ++n) b[n] = *(const bf16x8*)(W1l + k0 * 8192 + n * 512);
#pragma unroll
    for (int m = 0; m < 4; ++m)
#pragma unroll
      for (int n = 0; n < 4; ++n) acc[m][n] = MFMA16(a[m], b[n], acc[m][n]);
  }
  __syncthreads();  // xs dead before h half overlay

  const float* w320l = w320 + layer * 256;
  const float* b1l = b1 + layer * 256;
#pragma unroll
  for (int n = 0; n < 4; ++n) {
    int cg = wid * 64 + n * 16 + colq;
    float wv = w320l[cg], bv = b1l[cg];
#pragma unroll
    for (int m = 0; m < 4; ++m)
#pragma unroll
      for (int i = 0; i < 4; ++i) {
        int r = m * 16 + rsub + i;
        acc[m][n][i] = fmaxf(acc[m][n][i] + cl[r] * wv + bv, 0.f);
      }
  }
  if (wid < 2) {
#pragma unroll
    for (int m = 0; m < 4; ++m)
#pragma unroll
      for (int n = 0; n < 4; ++n)
#pragma unroll
        for (int i = 0; i < 4; ++i) {
          int r = m * 16 + rsub + i;
          int cc = wid * 64 + n * 16 + colq;
          bf16 hi, lo; split2(acc[m][n][i], hi, lo);
          hhi[r * HSS + cc] = hi;
          hlo[r * HSS + cc] = lo;
        }
  }
  __syncthreads();

  // ---- M2 split-K
  const bf16* W2h = W2blk + layer * 65536 + (wid * 32 + colq) * 32 + cq * 8;
  const bf16* W2l = W2h + 32768;
  const bf16* hhil = hhi + colq * HSS + cq * 8;
  const bf16* hlol = hlo + colq * HSS + cq * 8;
  f32x4 acc2[4][2];
#pragma unroll
  for (int m = 0; m < 4; ++m)
#pragma unroll
    for (int n = 0; n < 2; ++n) acc2[m][n] = (f32x4){0.f, 0.f, 0.f, 0.f};
#pragma unroll
  for (int kg = 0; kg < 8; ++kg) {
    if (kg == 4) {
      __syncthreads();
      if (wid >= 2) {
#pragma unroll
        for (int m = 0; m < 4; ++m)
#pragma unroll
          for (int n = 0; n < 4; ++n)
#pragma unroll
            for (int i = 0; i < 4; ++i) {
              int r = m * 16 + rsub + i;
              int cc = (wid & 1) * 64 + n * 16 + colq;
              bf16 hi, lo; split2(acc[m][n][i], hi, lo);
              hhi[r * HSS + cc] = hi;
              hlo[r * HSS + cc] = lo;
            }
      }
      __syncthreads();
    }
    int lk = (kg & 3) * 32;
    bf16x8 ahi[4], alo[4], bhi[2], blo[2];
#pragma unroll
    for (int m = 0; m < 4; ++m) {
      ahi[m] = *(const bf16x8*)(hhil + m * 16 * HSS + lk);
      alo[m] = *(const bf16x8*)(hlol + m * 16 * HSS + lk);
    }
#pragma unroll
    for (int n = 0; n < 2; ++n) {
      bhi[n] = *(const bf16x8*)(W2h + kg * 4096 + n * 512);
      blo[n] = *(const bf16x8*)(W2l + kg * 4096 + n * 512);
    }
#pragma unroll
    for (int m = 0; m < 4; ++m)
#pragma unroll
      for (int n = 0; n < 2; ++n) {
        acc2[m][n] = MFMA16(ahi[m], bhi[n], acc2[m][n]);
        acc2[m][n] = MFMA16(ahi[m], blo[n], acc2[m][n]);
        acc2[m][n] = MFMA16(alo[m], bhi[n], acc2[m][n]);
      }
  }
  __syncthreads();  // h dead before m overlay

  const float* b2l = b2 + layer * 128;
  const float* nbl = nb_out + ((long)(layer * 2 + side)) * NB_EV * ND;
#pragma unroll
  for (int n = 0; n < 2; ++n) {
    int cg = wid * 32 + n * 16 + colq;
    float bv = b2l[cg];
#pragma unroll
    for (int m = 0; m < 4; ++m)
#pragma unroll
      for (int i = 0; i < 4; ++i) {
        int r = m * 16 + rsub + i;
        float mval = acc2[m][n][i] + bv + nbl[(long)(b0r + r) * ND + cg];
        bf16 hi, lo; split2(mval, hi, lo);
        mhi[r * HSS + cg] = hi;
        mlo[r * HSS + cg] = lo;
      }
  }
  __syncthreads();

  // ---- GRU: gate order (r,z,n); wave owns rows wid*16..+15
  float* outP = side ? outB : outA;
  const int ostride = side ? ostrideB : ostrideA;
  const int rowA = wid * 16 + colq;
  const int rbase = wid * 16 + rsub;
  const bf16* mhil = mhi + rowA * HSS + cq * 8;
  const bf16* mlol = mlo + rowA * HSS + cq * 8;
  const bf16* ghil = ghi + rowA * HSS + cq * 8;
  const bf16* glol = glo + rowA * HSS + cq * 8;
  const bf16* wihl = wihblk + colq * 32 + cq * 8;
  const bf16* whhl = whhblk + colq * 32 + cq * 8;

  for (int jt = 0; jt < 8; ++jt) {
    f32x4 gx[3], gh[3];
#pragma unroll
    for (int g = 0; g < 3; ++g) {
      gx[g] = (f32x4){0.f, 0.f, 0.f, 0.f};
      gh[g] = (f32x4){0.f, 0.f, 0.f, 0.f};
    }
#pragma unroll
    for (int kc = 0; kc < 4; ++kc) {
      bf16x8 amh = *(const bf16x8*)(mhil + kc * 32);
      bf16x8 aml = *(const bf16x8*)(mlol + kc * 32);
      bf16x8 ahh = *(const bf16x8*)(ghil + kc * 32);
      bf16x8 ahl = *(const bf16x8*)(glol + kc * 32);
#pragma unroll
      for (int g = 0; g < 3; ++g) {
        int nb = (g * 128 + jt * 16) * 32;
        bf16x8 bh = *(const bf16x8*)(wihl + kc * 12288 + nb);
        bf16x8 bl = *(const bf16x8*)(wihl + 49152 + kc * 12288 + nb);
        gx[g] = MFMA16(amh, bh, gx[g]);
        gx[g] = MFMA16(aml, bh, gx[g]);
        gx[g] = MFMA16(amh, bl, gx[g]);
        bf16x8 ch = *(const bf16x8*)(whhl + kc * 12288 + nb);
        bf16x8 cl2 = *(const bf16x8*)(whhl + 49152 + kc * 12288 + nb);
        gh[g] = MFMA16(ahh, ch, gh[g]);
        gh[g] = MFMA16(ahl, ch, gh[g]);
        gh[g] = MFMA16(ahh, cl2, gh[g]);
      }
    }
    int j = jt * 16 + colq;
    float bihr = bih[j], bihz = bih[128 + j], bihn = bih[256 + j];
    float bhhr = bhh[j], bhhz = bhh[128 + j], bhhn = bhh[256 + j];
#pragma unroll
    for (int i = 0; i < 4; ++i) {
      int rr = rbase + i;
      float rx = gx[0][i] + bihr, zx = gx[1][i] + bihz, nx = gx[2][i] + bihn;
      float rh = gh[0][i] + bhhr, zh = gh[1][i] + bhhz, nh = gh[2][i] + bhhn;
      float r = 1.f / (1.f + expf(-(rx + rh)));
      float zz = 1.f / (1.f + expf(-(zx + zh)));
      float n = tanhf(nx + r * nh);
      float hval = (float)ghi[rr * HSS + j] + (float)glo[rr * HSS + j];
      outP[(long)(b0r + rr) * ostride + j] = (1.f - zz) * n + zz * hval;
    }
  }
}

// ---------------- launch ----------------
extern "C" void kernel_launch(void* const* d_in, const int* in_sizes, int n_in,
                              void* d_out, int out_size, void* d_ws, size_t ws_size,
                              hipStream_t stream) {
  const int* srcn = (const int*)d_in[0];
  const int* dstn = (const int*)d_in[1];
  const float* edge_attrs = (const float*)d_in[2];
  const float* timestamps = (const float*)d_in[3];
  const float* memory = (const float*)d_in[4];
  const int* neighbor_ids = (const int*)d_in[5];
  const float* neighbor_times = (const float*)d_in[6];
  const float* neighbor_edge_attrs = (const float*)d_in[7];
  const float* t2v_w0 = (const float*)d_in[8];
  const float* t2v_b0 = (const float*)d_in[9];
  const float* t2v_w = (const float*)d_in[10];
  const float* t2v_b = (const float*)d_in[11];
  const float* enc_W = (const float*)d_in[12];
  const float* enc_b = (const float*)d_in[13];
  const float* mlp_W1 = (const float*)d_in[14];
  const float* mlp_b1 = (const float*)d_in[15];
  const float* mlp_W2 = (const float*)d_in[16];
  const float* mlp_b2 = (const float*)d_in[17];
  const float* gru_w_ih = (const float*)d_in[18];
  const float* gru_w_hh = (const float*)d_in[19];
  const float* gru_b_ih = (const float*)d_in[20];
  const float* gru_b_hh = (const float*)d_in[21];

  char* ws = (char*)d_ws;
  size_t off = 0;
  auto alloc = [&](size_t bytes) { size_t o = off; off += (bytes + 255) & ~(size_t)255; return o; };
  bf16* W1blk = (bf16*)(ws + alloc((size_t)2 * 11 * 256 * 32 * 2));
  bf16* W2blk = (bf16*)(ws + alloc((size_t)2 * 2 * 8 * 128 * 32 * 2));
  bf16* wihblk = (bf16*)(ws + alloc((size_t)2 * 4 * 384 * 32 * 2));
  bf16* whhblk = (bf16*)(ws + alloc((size_t)2 * 4 * 384 * 32 * 2));
  float* w320 = (float*)(ws + alloc(512 * 4));
  float* time_emb = (float*)(ws + alloc((size_t)NB_EV * 32 * 4));
  float* edge_enc = (float*)(ws + alloc((size_t)NB_EV * 64 * 4));
  float* embA0 = (float*)(ws + alloc((size_t)NB_EV * ND * 4));
  float* embB0 = (float*)(ws + alloc((size_t)NB_EV * ND * 4));
  float* embA1 = (float*)(ws + alloc((size_t)NB_EV * ND * 4));
  float* embB1 = (float*)(ws + alloc((size_t)NB_EV * ND * 4));
  float* nb_out = (float*)(ws + alloc((size_t)4 * NB_EV * ND * 4));

  k_prep_weights<<<512, 256, 0, stream>>>(mlp_W1, mlp_W2, gru_w_ih, gru_w_hh,
                                          W1blk, W2blk, wihblk, whhblk, w320);
  k_prep_misc<<<2048, 256, 0, stream>>>(timestamps, t2v_w0, t2v_b0, t2v_w, t2v_b,
                                        srcn, dstn, memory, time_emb, embA0, embB0, nb_out);
  k_edge<<<NB_EV, 64, 0, stream>>>(edge_attrs, enc_W, enc_b, edge_enc);

  k_nbr<<<dim3(ROWS_NB / 64, 2, 1), 256, 0, stream>>>(
      srcn, dstn, memory, neighbor_ids, neighbor_times, neighbor_edge_attrs,
      t2v_w0, t2v_b0, t2v_w, t2v_b, W1blk, W2blk, w320, mlp_b1, mlp_b2, nb_out);

  k_event<<<2 * NB_EV / 64, 256, 0, stream>>>(
      0, embA0, embB0, embA1, ND, embB1, ND, time_emb, edge_enc,
      W1blk, W2blk, w320, mlp_b1, mlp_b2, nb_out,
      wihblk, whhblk, gru_b_ih, gru_b_hh);

  float* outf = (float*)d_out;
  k_event<<<2 * NB_EV / 64, 256, 0, stream>>>(
      1, embA1, embB1, outf, 2 * ND, outf + ND, 2 * ND, time_emb, edge_enc,
      W1blk, W2blk, w320, mlp_b1, mlp_b2, nb_out,
      wihblk, whhblk, gru_b_ih, gru_b_hh);
}

// Round 5
// 714.531 us; speedup vs baseline: 3.3389x; 1.1509x over previous
//
#include <hip/hip_runtime.h>
#include <math.h>

// TemporalGraphTower on MI355X (gfx950) — round 5.
// k_nbr rewritten: distance-2 software-pipelined weight-frag loads (rolling
// register buffers, static indices) + transpose-mode MFMA (A=weight,
// B=activation) so exchange dumps are packed ds_write_b64 / float4.
// k_event identical to round 4 (passing).

typedef __bf16 bf16;
typedef __bf16 bf16x8 __attribute__((ext_vector_type(8)));
typedef float f32x4 __attribute__((ext_vector_type(4)));

#define MFMA16(a, b, c) __builtin_amdgcn_mfma_f32_16x16x32_bf16((a), (b), (c), 0, 0, 0)

__device__ __forceinline__ void split2(float v, bf16& hi, bf16& lo) {
  hi = (bf16)v;
  lo = (bf16)(v - (float)hi);
}

#define NB_EV 8192
#define ROWS_NB (NB_EV * 20)   // 163840
#define IN_DIM 352
#define HID 256
#define ND 128

// ---------------- prep: blocked weight layouts (all bf16 / hi-lo split) ----
// W1blk  [2 l][11 k0][256 n][32 k]          (frag = contiguous 1KB/wave)
// W2blk  [2 l][2 plane][8 kg][128 n][32 k]
// wihblk/whhblk [2 plane][4 kg][384 n][32 k]
// w320 f32 [2][256] — exact fp32 rank-1 fix for the big time column
__global__ void k_prep_weights(const float* __restrict__ W1, const float* __restrict__ W2,
                               const float* __restrict__ wih, const float* __restrict__ whh,
                               bf16* __restrict__ W1blk, bf16* __restrict__ W2blk,
                               bf16* __restrict__ wihblk, bf16* __restrict__ whhblk,
                               float* __restrict__ w320) {
  const int NW1 = 2 * 11 * 256 * 32;   // 180224
  const int NW2 = 2 * 2 * 8 * 128 * 32; // 131072
  const int NG = 2 * 4 * 384 * 32;     // 98304
  int total = NW1 + NW2 + NG + NG + 512;
  for (int i = blockIdx.x * blockDim.x + threadIdx.x; i < total; i += gridDim.x * blockDim.x) {
    int j = i;
    if (j < NW1) {
      int l = j / 90112, r = j - l * 90112;
      int k0 = r / 8192, r2 = r & 8191;
      int n = r2 >> 5, ko = r2 & 31, k = k0 * 32 + ko;
      W1blk[j] = (bf16)W1[(l * 352 + k) * 256 + n];
    } else if ((j -= NW1) < NW2) {
      int l = j >> 16, r = j & 65535;
      int plane = r >> 15, r2 = r & 32767;
      int kg = r2 >> 12, r3 = r2 & 4095;
      int n = r3 >> 5, ko = r3 & 31, k = kg * 32 + ko;
      bf16 hi, lo; split2(W2[(l * 256 + k) * 128 + n], hi, lo);
      W2blk[j] = plane ? lo : hi;
    } else if ((j -= NW2) < NG) {
      int plane = j / 49152, r = j - plane * 49152;
      int kg = r / 12288, r2 = r - kg * 12288;
      int n = r2 >> 5, ko = r2 & 31, k = kg * 32 + ko;
      bf16 hi, lo; split2(wih[n * 128 + k], hi, lo);
      wihblk[j] = plane ? lo : hi;
    } else if ((j -= NG) < NG) {
      int plane = j / 49152, r = j - plane * 49152;
      int kg = r / 12288, r2 = r - kg * 12288;
      int n = r2 >> 5, ko = r2 & 31, k = kg * 32 + ko;
      bf16 hi, lo; split2(whh[n * 128 + k], hi, lo);
      whhblk[j] = plane ? lo : hi;
    } else {
      j -= NG;
      int l = j >> 8, n = j & 255;
      w320[j] = W1[(l * 352 + 320) * 256 + n];
    }
  }
}

// time2vec table [B][32], initial embedding gathers, zero nb accumulators
__global__ void k_prep_misc(const float* __restrict__ ts, const float* __restrict__ w0,
                            const float* __restrict__ b0, const float* __restrict__ w,
                            const float* __restrict__ bb,
                            const int* __restrict__ srcn, const int* __restrict__ dstn,
                            const float* __restrict__ memory,
                            float* __restrict__ time_emb, float* __restrict__ embA0,
                            float* __restrict__ embB0, float* __restrict__ nb_out) {
  const int N1 = NB_EV * 32, N2 = NB_EV * ND, N3 = 4 * NB_EV * ND;
  int total = N1 + N2 + N3;
  float w0v = w0[0], b0v = b0[0];
  for (int i = blockIdx.x * blockDim.x + threadIdx.x; i < total; i += gridDim.x * blockDim.x) {
    int j = i;
    if (j < N1) {
      int b = j >> 5, c = j & 31;
      float t = ts[b];
      time_emb[j] = (c == 0) ? (w0v * t + b0v) : sinf(w[c - 1] * t + bb[c - 1]);
    } else if ((j -= N1) < N2) {
      int b = j >> 7, c = j & 127;
      embA0[j] = memory[(long)srcn[b] * ND + c];
      embB0[j] = memory[(long)dstn[b] * ND + c];
    } else {
      nb_out[j - N2] = 0.f;
    }
  }
}

// edge_enc[b][j] = sum_k edge_attrs[b][k]*enc_W[k][j] + enc_b[j]
__global__ void k_edge(const float* __restrict__ ea, const float* __restrict__ encW,
                       const float* __restrict__ encb, float* __restrict__ out) {
  __shared__ float row[64];
  int b = blockIdx.x, j = threadIdx.x;
  row[j] = ea[b * 64 + j];
  __syncthreads();
  float s = encb[j];
#pragma unroll
  for (int k = 0; k < 64; ++k) s += row[k] * encW[k * 64 + j];
  out[b * 64 + j] = s;
}

// ---------------- fused neighbor: gather + 2x(M1,M2) + mean ----------------
// T-mode: A = weight-frag, B = activation-frag. Output: lane = (row r, 4
// consecutive out-cols) -> packed b64 plane dumps. Distance-2 prefetch of
// weight frags (rolling reg buffers), distance-1 of LDS x-frags.
#define XSS 360        // xs stride (elems)
#define HSS 136        // h half-plane stride (elems)
#define MSS 132        // mrow stride (f32)
#define L_H 46080      // hhi @46080, hlo @63488 ; mrow overlays @46080
#define L_CL 80896
#define L_TOT 81152
__global__ __launch_bounds__(256, 2) void k_nbr(
    const int* __restrict__ srcn, const int* __restrict__ dstn,
    const float* __restrict__ memory, const int* __restrict__ nbids,
    const float* __restrict__ nbt, const float* __restrict__ nbe,
    const float* __restrict__ w0p, const float* __restrict__ b0p,
    const float* __restrict__ wp, const float* __restrict__ bp,
    const bf16* __restrict__ W1blk, const bf16* __restrict__ W2blk,
    const float* __restrict__ w320, const float* __restrict__ b1,
    const float* __restrict__ b2, float* __restrict__ nb_out) {
  __shared__ __align__(16) char smem[L_TOT];
  bf16* xs = (bf16*)(smem);
  bf16* hhi = (bf16*)(smem + L_H);
  bf16* hlo = (bf16*)(smem + L_H + 17408);
  float* mrow = (float*)(smem + L_H);
  float* cl = (float*)(smem + L_CL);
  // gather temps live in the (not yet used) h region
  int* nbid_l = (int*)(smem + L_H);
  int* n_l = nbid_l + 64;
  int* flat_l = n_l + 64;
  float* t_l = (float*)(flat_l + 64);

  const int tid = threadIdx.x;
  const int side = blockIdx.y;
  const int r0 = blockIdx.x * 64;
  const int* nodes = side ? dstn : srcn;

  if (tid < 64) {
    int rg = r0 + tid;
    int b = rg / 20, k = rg - b * 20;
    int n = nodes[b];
    int flat = n * 20 + k;
    nbid_l[tid] = nbids[flat];
    n_l[tid] = n;
    flat_l[tid] = flat;
    float t = nbt[flat];
    t_l[tid] = t;
    cl[tid] = w0p[0] * t + b0p[0];
  }
  __syncthreads();

  // build x tile into LDS: [nb_emb(128) | node_mem(128) | nb_e(64) | t2v(32, col0=0)]
  for (int task = tid; task < 64 * 88; task += 256) {
    int r = task / 88; int c = (task - r * 88) * 4;
    float4 v;
    if (c < 128) {
      v = *(const float4*)&memory[(long)nbid_l[r] * ND + c];
    } else if (c < 256) {
      v = *(const float4*)&memory[(long)n_l[r] * ND + (c - 128)];
    } else if (c < 320) {
      v = *(const float4*)&nbe[(long)flat_l[r] * 64 + (c - 256)];
    } else {
      float t = t_l[r];
      float vv[4];
#pragma unroll
      for (int q = 0; q < 4; ++q) {
        int cc = c + q - 320;
        vv[q] = (cc == 0) ? 0.f : __sinf(wp[cc - 1] * t + bp[cc - 1]);
      }
      v = make_float4(vv[0], vv[1], vv[2], vv[3]);
    }
    union { bf16 h[4]; uint2 u; } pk;
    pk.h[0] = (bf16)v.x; pk.h[1] = (bf16)v.y; pk.h[2] = (bf16)v.z; pk.h[3] = (bf16)v.w;
    *(uint2*)&xs[r * XSS + c] = pk.u;
  }
  __syncthreads();

  const int wid = tid >> 6, lane = tid & 63;
  const int colq = lane & 15, cq = lane >> 4;

  for (int layer = 0; layer < 2; ++layer) {
    // ---- M1-T: hT = W1^T-frags (A) x x-frags (B); wave owns 64 h-cols.
    const bf16* W1l = W1blk + layer * 90112 + (wid * 64 + colq) * 32 + cq * 8;
    const bf16* xsl = xs + colq * XSS + cq * 8;

    f32x4 acc[4][4];   // [mc][nr]
#pragma unroll
    for (int mc = 0; mc < 4; ++mc)
#pragma unroll
      for (int nr = 0; nr < 4; ++nr) acc[mc][nr] = (f32x4){0.f, 0.f, 0.f, 0.f};

    bf16x8 wz[3][4];   // distance-2 rolling buffer (static indices after unroll)
#pragma unroll
    for (int s = 0; s < 2; ++s)
#pragma unroll
      for (int mc = 0; mc < 4; ++mc)
        wz[s][mc] = *(const bf16x8*)(W1l + s * 8192 + mc * 512);
    bf16x8 xz[2][4];
#pragma unroll
    for (int nr = 0; nr < 4; ++nr) xz[0][nr] = *(const bf16x8*)(xsl + nr * 16 * XSS);

#pragma unroll
    for (int k0 = 0; k0 < 11; ++k0) {
      if (k0 < 9) {
#pragma unroll
        for (int mc = 0; mc < 4; ++mc)
          wz[(k0 + 2) % 3][mc] = *(const bf16x8*)(W1l + (k0 + 2) * 8192 + mc * 512);
      }
      if (k0 < 10) {
#pragma unroll
        for (int nr = 0; nr < 4; ++nr)
          xz[(k0 + 1) & 1][nr] = *(const bf16x8*)(xsl + nr * 16 * XSS + (k0 + 1) * 32);
      }
#pragma unroll
      for (int mc = 0; mc < 4; ++mc)
#pragma unroll
        for (int nr = 0; nr < 4; ++nr)
          acc[mc][nr] = MFMA16(wz[k0 % 3][mc], xz[k0 & 1][nr], acc[mc][nr]);
    }

    // rank-1 time fix + bias + relu (lane holds r fixed, 4 consecutive c)
    const float* w320l = w320 + layer * 256;
    const float* b1l = b1 + layer * 256;
#pragma unroll
    for (int mc = 0; mc < 4; ++mc) {
      int c0 = wid * 64 + mc * 16 + cq * 4;
      float4 wv = *(const float4*)&w320l[c0];
      float4 bv = *(const float4*)&b1l[c0];
#pragma unroll
      for (int nr = 0; nr < 4; ++nr) {
        float clr = cl[nr * 16 + colq];
        acc[mc][nr][0] = fmaxf(acc[mc][nr][0] + clr * wv.x + bv.x, 0.f);
        acc[mc][nr][1] = fmaxf(acc[mc][nr][1] + clr * wv.y + bv.y, 0.f);
        acc[mc][nr][2] = fmaxf(acc[mc][nr][2] + clr * wv.z + bv.z, 0.f);
        acc[mc][nr][3] = fmaxf(acc[mc][nr][3] + clr * wv.w + bv.w, 0.f);
      }
    }

    // half1 dump (h cols 0..127 = waves 0,1), packed b64 per plane
    if (wid < 2) {
#pragma unroll
      for (int mc = 0; mc < 4; ++mc)
#pragma unroll
        for (int nr = 0; nr < 4; ++nr) {
          int r = nr * 16 + colq;
          int ch = wid * 64 + mc * 16 + cq * 4;
          union { bf16 h[4]; uint2 u; } ph, pl;
#pragma unroll
          for (int i = 0; i < 4; ++i) split2(acc[mc][nr][i], ph.h[i], pl.h[i]);
          *(uint2*)&hhi[r * HSS + ch] = ph.u;
          *(uint2*)&hlo[r * HSS + ch] = pl.u;
        }
    }
    __syncthreads();

    // ---- M2-T split-K: mT = W2-frags (A) x h-frags (B), 3 hi/lo products
    const bf16* W2h = W2blk + layer * 65536 + (wid * 32 + colq) * 32 + cq * 8;
    const bf16* W2l = W2h + 32768;
    const bf16* hhil = hhi + colq * HSS + cq * 8;
    const bf16* hlol = hlo + colq * HSS + cq * 8;

    f32x4 acc2[2][4];  // [mc2][nr]
#pragma unroll
    for (int mc2 = 0; mc2 < 2; ++mc2)
#pragma unroll
      for (int nr = 0; nr < 4; ++nr) acc2[mc2][nr] = (f32x4){0.f, 0.f, 0.f, 0.f};

    bf16x8 w2z[3][4];  // [slot][mc2*2+plane]
#pragma unroll
    for (int s = 0; s < 2; ++s)
#pragma unroll
      for (int mc2 = 0; mc2 < 2; ++mc2) {
        w2z[s][mc2 * 2 + 0] = *(const bf16x8*)(W2h + s * 4096 + mc2 * 512);
        w2z[s][mc2 * 2 + 1] = *(const bf16x8*)(W2l + s * 4096 + mc2 * 512);
      }

#pragma unroll
    for (int kg = 0; kg < 8; ++kg) {
      if (kg == 4) {
        __syncthreads();  // half1 reads done
        if (wid >= 2) {   // half2 dump (h cols 128..255 -> local 0..127)
#pragma unroll
          for (int mc = 0; mc < 4; ++mc)
#pragma unroll
            for (int nr = 0; nr < 4; ++nr) {
              int r = nr * 16 + colq;
              int ch = (wid & 1) * 64 + mc * 16 + cq * 4;
              union { bf16 h[4]; uint2 u; } ph, pl;
#pragma unroll
              for (int i = 0; i < 4; ++i) split2(acc[mc][nr][i], ph.h[i], pl.h[i]);
              *(uint2*)&hhi[r * HSS + ch] = ph.u;
              *(uint2*)&hlo[r * HSS + ch] = pl.u;
            }
        }
        __syncthreads();
      }
      if (kg < 6) {
        int s2 = (kg + 2) % 3;
#pragma unroll
        for (int mc2 = 0; mc2 < 2; ++mc2) {
          w2z[s2][mc2 * 2 + 0] = *(const bf16x8*)(W2h + (kg + 2) * 4096 + mc2 * 512);
          w2z[s2][mc2 * 2 + 1] = *(const bf16x8*)(W2l + (kg + 2) * 4096 + mc2 * 512);
        }
      }
      int lk = (kg & 3) * 32;
      bf16x8 bh[4], bl[4];
#pragma unroll
      for (int nr = 0; nr < 4; ++nr) {
        bh[nr] = *(const bf16x8*)(hhil + nr * 16 * HSS + lk);
        bl[nr] = *(const bf16x8*)(hlol + nr * 16 * HSS + lk);
      }
      int s = kg % 3;
#pragma unroll
      for (int mc2 = 0; mc2 < 2; ++mc2)
#pragma unroll
        for (int nr = 0; nr < 4; ++nr) {
          acc2[mc2][nr] = MFMA16(w2z[s][mc2 * 2 + 0], bh[nr], acc2[mc2][nr]);
          acc2[mc2][nr] = MFMA16(w2z[s][mc2 * 2 + 1], bh[nr], acc2[mc2][nr]);
          acc2[mc2][nr] = MFMA16(w2z[s][mc2 * 2 + 0], bl[nr], acc2[mc2][nr]);
        }
    }
    __syncthreads();  // h dead -> mrow overlay

    const float* b2l = b2 + layer * 128;
#pragma unroll
    for (int mc2 = 0; mc2 < 2; ++mc2) {
      int c0 = wid * 32 + mc2 * 16 + cq * 4;
      float4 bv = *(const float4*)&b2l[c0];
#pragma unroll
      for (int nr = 0; nr < 4; ++nr) {
        int r = nr * 16 + colq;
        float4 mv;
        mv.x = (acc2[mc2][nr][0] + bv.x) * 0.05f;
        mv.y = (acc2[mc2][nr][1] + bv.y) * 0.05f;
        mv.z = (acc2[mc2][nr][2] + bv.z) * 0.05f;
        mv.w = (acc2[mc2][nr][3] + bv.w) * 0.05f;
        *(float4*)&mrow[r * MSS + c0] = mv;
      }
    }
    __syncthreads();

    // mean over k within tile, atomic-accumulate per event
    {
      int colr = tid & 127, half = tid >> 7;
      int bf0 = r0 / 20;
      long zbase = (long)(layer * 2 + side) * NB_EV * ND;
      for (int bi = half; bi <= 4; bi += 2) {
        int b = bf0 + bi;
        if (b >= NB_EV) break;
        int rlo = b * 20 - r0, rhi = rlo + 20;
        rlo = max(rlo, 0); rhi = min(rhi, 64);
        if (rlo >= rhi) continue;
        float s = 0.f;
        for (int r = rlo; r < rhi; ++r) s += mrow[r * MSS + colr];
        atomicAdd(&nb_out[zbase + (long)b * ND + colr], s);
      }
    }
    __syncthreads();  // mrow dead before next layer's h dump
  }
}

// ---------------- event chain: MLP + GRU (one launch per layer) ----------------
// identical to round 4 (passing)
#define E_G 46080      // ghi @46080, glo @63488 (persist)
#define E_CL 80896
#define E_TOT 81152
__global__ __launch_bounds__(256, 1) void k_event(
    int layer, const float* __restrict__ embA_in, const float* __restrict__ embB_in,
    float* __restrict__ outA, int ostrideA, float* __restrict__ outB, int ostrideB,
    const float* __restrict__ time_emb, const float* __restrict__ edge_enc,
    const bf16* __restrict__ W1blk, const bf16* __restrict__ W2blk,
    const float* __restrict__ w320, const float* __restrict__ b1,
    const float* __restrict__ b2, const float* __restrict__ nb_out,
    const bf16* __restrict__ wihblk, const bf16* __restrict__ whhblk,
    const float* __restrict__ bih, const float* __restrict__ bhh) {
  __shared__ __align__(16) char smem[E_TOT];
  bf16* xs = (bf16*)(smem);
  bf16* hhi = (bf16*)(smem);                 // half-plane, overlays xs after M1
  bf16* hlo = (bf16*)(smem + 17408);
  bf16* mhi = (bf16*)(smem);                 // overlays h after M2
  bf16* mlo = (bf16*)(smem + 17408);
  bf16* ghi = (bf16*)(smem + E_G);
  bf16* glo = (bf16*)(smem + E_G + 17408);
  float* cl = (float*)(smem + E_CL);

  const int tid = threadIdx.x;
  const int r0 = blockIdx.x * 64;
  const int side = r0 >> 13;
  const int b0r = r0 & (NB_EV - 1);
  const float* ea = side ? embB_in : embA_in;   // own embedding (GRU h)
  const float* eb = side ? embA_in : embB_in;

  if (tid < 64) cl[tid] = time_emb[(b0r + tid) * 32];

  for (int task = tid; task < 64 * 88; task += 256) {
    int r = task / 88; int c = (task - r * 88) * 4;
    int b = b0r + r;
    float4 v;
    if (c < 128) {
      v = *(const float4*)&ea[(long)b * ND + c];
      bf16 h0, l0, h1, l1, h2, l2, h3, l3;
      split2(v.x, h0, l0); split2(v.y, h1, l1); split2(v.z, h2, l2); split2(v.w, h3, l3);
      ghi[r * HSS + c + 0] = h0; glo[r * HSS + c + 0] = l0;
      ghi[r * HSS + c + 1] = h1; glo[r * HSS + c + 1] = l1;
      ghi[r * HSS + c + 2] = h2; glo[r * HSS + c + 2] = l2;
      ghi[r * HSS + c + 3] = h3; glo[r * HSS + c + 3] = l3;
    } else if (c < 256) {
      v = *(const float4*)&eb[(long)b * ND + (c - 128)];
    } else if (c < 320) {
      v = *(const float4*)&edge_enc[(long)b * 64 + (c - 256)];
    } else {
      float vv[4];
#pragma unroll
      for (int q = 0; q < 4; ++q) {
        int cc = c + q - 320;
        vv[q] = (cc == 0) ? 0.f : time_emb[b * 32 + cc];
      }
      v = make_float4(vv[0], vv[1], vv[2], vv[3]);
    }
    union { bf16 h[4]; uint2 u; } pk;
    pk.h[0] = (bf16)v.x; pk.h[1] = (bf16)v.y; pk.h[2] = (bf16)v.z; pk.h[3] = (bf16)v.w;
    *(uint2*)&xs[r * XSS + c] = pk.u;
  }
  __syncthreads();

  const int wid = tid >> 6, lane = tid & 63;
  const int colq = lane & 15, cq = lane >> 4;
  const int rsub = cq * 4;

  // ---- M1
  const bf16* W1l = W1blk + layer * 90112 + (wid * 64 + colq) * 32 + cq * 8;
  const bf16* xsl = xs + colq * XSS + cq * 8;
  f32x4 acc[4][4];
#pragma unroll
  for (int m = 0; m < 4; ++m)
#pragma unroll
    for (int n = 0; n < 4; ++n) acc[m][n] = (f32x4){0.f, 0.f, 0.f, 0.f};
#pragma unroll
  for (int k0 = 0; k0 < 11; ++k0) {
    bf16x8 a[4], b[4];
#pragma unroll
    for (int m = 0; m < 4; ++m) a[m] = *(const bf16x8*)(xsl + m * 16 * XSS + k0 * 32);
#pragma unroll
    for (int n = 0; n < 4; ++n) b[n] = *(const bf16x8*)(W1l + k0 * 8192 + n * 512);
#pragma unroll
    for (int m = 0; m < 4; ++m)
#pragma unroll
      for (int n = 0; n < 4; ++n) acc[m][n] = MFMA16(a[m], b[n], acc[m][n]);
  }
  __syncthreads();  // xs dead before h half overlay

  const float* w320l = w320 + layer * 256;
  const float* b1l = b1 + layer * 256;
#pragma unroll
  for (int n = 0; n < 4; ++n) {
    int cg = wid * 64 + n * 16 + colq;
    float wv = w320l[cg], bv = b1l[cg];
#pragma unroll
    for (int m = 0; m < 4; ++m)
#pragma unroll
      for (int i = 0; i < 4; ++i) {
        int r = m * 16 + rsub + i;
        acc[m][n][i] = fmaxf(acc[m][n][i] + cl[r] * wv + bv, 0.f);
      }
  }
  if (wid < 2) {
#pragma unroll
    for (int m = 0; m < 4; ++m)
#pragma unroll
      for (int n = 0; n < 4; ++n)
#pragma unroll
        for (int i = 0; i < 4; ++i) {
          int r = m * 16 + rsub + i;
          int cc = wid * 64 + n * 16 + colq;
          bf16 hi, lo; split2(acc[m][n][i], hi, lo);
          hhi[r * HSS + cc] = hi;
          hlo[r * HSS + cc] = lo;
        }
  }
  __syncthreads();

  // ---- M2 split-K
  const bf16* W2h = W2blk + layer * 65536 + (wid * 32 + colq) * 32 + cq * 8;
  const bf16* W2l = W2h + 32768;
  const bf16* hhil = hhi + colq * HSS + cq * 8;
  const bf16* hlol = hlo + colq * HSS + cq * 8;
  f32x4 acc2[4][2];
#pragma unroll
  for (int m = 0; m < 4; ++m)
#pragma unroll
    for (int n = 0; n < 2; ++n) acc2[m][n] = (f32x4){0.f, 0.f, 0.f, 0.f};
#pragma unroll
  for (int kg = 0; kg < 8; ++kg) {
    if (kg == 4) {
      __syncthreads();
      if (wid >= 2) {
#pragma unroll
        for (int m = 0; m < 4; ++m)
#pragma unroll
          for (int n = 0; n < 4; ++n)
#pragma unroll
            for (int i = 0; i < 4; ++i) {
              int r = m * 16 + rsub + i;
              int cc = (wid & 1) * 64 + n * 16 + colq;
              bf16 hi, lo; split2(acc[m][n][i], hi, lo);
              hhi[r * HSS + cc] = hi;
              hlo[r * HSS + cc] = lo;
            }
      }
      __syncthreads();
    }
    int lk = (kg & 3) * 32;
    bf16x8 ahi[4], alo[4], bhi[2], blo[2];
#pragma unroll
    for (int m = 0; m < 4; ++m) {
      ahi[m] = *(const bf16x8*)(hhil + m * 16 * HSS + lk);
      alo[m] = *(const bf16x8*)(hlol + m * 16 * HSS + lk);
    }
#pragma unroll
    for (int n = 0; n < 2; ++n) {
      bhi[n] = *(const bf16x8*)(W2h + kg * 4096 + n * 512);
      blo[n] = *(const bf16x8*)(W2l + kg * 4096 + n * 512);
    }
#pragma unroll
    for (int m = 0; m < 4; ++m)
#pragma unroll
      for (int n = 0; n < 2; ++n) {
        acc2[m][n] = MFMA16(ahi[m], bhi[n], acc2[m][n]);
        acc2[m][n] = MFMA16(ahi[m], blo[n], acc2[m][n]);
        acc2[m][n] = MFMA16(alo[m], bhi[n], acc2[m][n]);
      }
  }
  __syncthreads();  // h dead before m overlay

  const float* b2l = b2 + layer * 128;
  const float* nbl = nb_out + ((long)(layer * 2 + side)) * NB_EV * ND;
#pragma unroll
  for (int n = 0; n < 2; ++n) {
    int cg = wid * 32 + n * 16 + colq;
    float bv = b2l[cg];
#pragma unroll
    for (int m = 0; m < 4; ++m)
#pragma unroll
      for (int i = 0; i < 4; ++i) {
        int r = m * 16 + rsub + i;
        float mval = acc2[m][n][i] + bv + nbl[(long)(b0r + r) * ND + cg];
        bf16 hi, lo; split2(mval, hi, lo);
        mhi[r * HSS + cg] = hi;
        mlo[r * HSS + cg] = lo;
      }
  }
  __syncthreads();

  // ---- GRU: gate order (r,z,n); wave owns rows wid*16..+15
  float* outP = side ? outB : outA;
  const int ostride = side ? ostrideB : ostrideA;
  const int rowA = wid * 16 + colq;
  const int rbase = wid * 16 + rsub;
  const bf16* mhil = mhi + rowA * HSS + cq * 8;
  const bf16* mlol = mlo + rowA * HSS + cq * 8;
  const bf16* ghil = ghi + rowA * HSS + cq * 8;
  const bf16* glol = glo + rowA * HSS + cq * 8;
  const bf16* wihl = wihblk + colq * 32 + cq * 8;
  const bf16* whhl = whhblk + colq * 32 + cq * 8;

  for (int jt = 0; jt < 8; ++jt) {
    f32x4 gx[3], gh[3];
#pragma unroll
    for (int g = 0; g < 3; ++g) {
      gx[g] = (f32x4){0.f, 0.f, 0.f, 0.f};
      gh[g] = (f32x4){0.f, 0.f, 0.f, 0.f};
    }
#pragma unroll
    for (int kc = 0; kc < 4; ++kc) {
      bf16x8 amh = *(const bf16x8*)(mhil + kc * 32);
      bf16x8 aml = *(const bf16x8*)(mlol + kc * 32);
      bf16x8 ahh = *(const bf16x8*)(ghil + kc * 32);
      bf16x8 ahl = *(const bf16x8*)(glol + kc * 32);
#pragma unroll
      for (int g = 0; g < 3; ++g) {
        int nb = (g * 128 + jt * 16) * 32;
        bf16x8 bh = *(const bf16x8*)(wihl + kc * 12288 + nb);
        bf16x8 bl = *(const bf16x8*)(wihl + 49152 + kc * 12288 + nb);
        gx[g] = MFMA16(amh, bh, gx[g]);
        gx[g] = MFMA16(aml, bh, gx[g]);
        gx[g] = MFMA16(amh, bl, gx[g]);
        bf16x8 ch = *(const bf16x8*)(whhl + kc * 12288 + nb);
        bf16x8 cl2 = *(const bf16x8*)(whhl + 49152 + kc * 12288 + nb);
        gh[g] = MFMA16(ahh, ch, gh[g]);
        gh[g] = MFMA16(ahl, ch, gh[g]);
        gh[g] = MFMA16(ahh, cl2, gh[g]);
      }
    }
    int j = jt * 16 + colq;
    float bihr = bih[j], bihz = bih[128 + j], bihn = bih[256 + j];
    float bhhr = bhh[j], bhhz = bhh[128 + j], bhhn = bhh[256 + j];
#pragma unroll
    for (int i = 0; i < 4; ++i) {
      int rr = rbase + i;
      float rx = gx[0][i] + bihr, zx = gx[1][i] + bihz, nx = gx[2][i] + bihn;
      float rh = gh[0][i] + bhhr, zh = gh[1][i] + bhhz, nh = gh[2][i] + bhhn;
      float r = 1.f / (1.f + expf(-(rx + rh)));
      float zz = 1.f / (1.f + expf(-(zx + zh)));
      float n = tanhf(nx + r * nh);
      float hval = (float)ghi[rr * HSS + j] + (float)glo[rr * HSS + j];
      outP[(long)(b0r + rr) * ostride + j] = (1.f - zz) * n + zz * hval;
    }
  }
}

// ---------------- launch ----------------
extern "C" void kernel_launch(void* const* d_in, const int* in_sizes, int n_in,
                              void* d_out, int out_size, void* d_ws, size_t ws_size,
                              hipStream_t stream) {
  const int* srcn = (const int*)d_in[0];
  const int* dstn = (const int*)d_in[1];
  const float* edge_attrs = (const float*)d_in[2];
  const float* timestamps = (const float*)d_in[3];
  const float* memory = (const float*)d_in[4];
  const int* neighbor_ids = (const int*)d_in[5];
  const float* neighbor_times = (const float*)d_in[6];
  const float* neighbor_edge_attrs = (const float*)d_in[7];
  const float* t2v_w0 = (const float*)d_in[8];
  const float* t2v_b0 = (const float*)d_in[9];
  const float* t2v_w = (const float*)d_in[10];
  const float* t2v_b = (const float*)d_in[11];
  const float* enc_W = (const float*)d_in[12];
  const float* enc_b = (const float*)d_in[13];
  const float* mlp_W1 = (const float*)d_in[14];
  const float* mlp_b1 = (const float*)d_in[15];
  const float* mlp_W2 = (const float*)d_in[16];
  const float* mlp_b2 = (const float*)d_in[17];
  const float* gru_w_ih = (const float*)d_in[18];
  const float* gru_w_hh = (const float*)d_in[19];
  const float* gru_b_ih = (const float*)d_in[20];
  const float* gru_b_hh = (const float*)d_in[21];

  char* ws = (char*)d_ws;
  size_t off = 0;
  auto alloc = [&](size_t bytes) { size_t o = off; off += (bytes + 255) & ~(size_t)255; return o; };
  bf16* W1blk = (bf16*)(ws + alloc((size_t)2 * 11 * 256 * 32 * 2));
  bf16* W2blk = (bf16*)(ws + alloc((size_t)2 * 2 * 8 * 128 * 32 * 2));
  bf16* wihblk = (bf16*)(ws + alloc((size_t)2 * 4 * 384 * 32 * 2));
  bf16* whhblk = (bf16*)(ws + alloc((size_t)2 * 4 * 384 * 32 * 2));
  float* w320 = (float*)(ws + alloc(512 * 4));
  float* time_emb = (float*)(ws + alloc((size_t)NB_EV * 32 * 4));
  float* edge_enc = (float*)(ws + alloc((size_t)NB_EV * 64 * 4));
  float* embA0 = (float*)(ws + alloc((size_t)NB_EV * ND * 4));
  float* embB0 = (float*)(ws + alloc((size_t)NB_EV * ND * 4));
  float* embA1 = (float*)(ws + alloc((size_t)NB_EV * ND * 4));
  float* embB1 = (float*)(ws + alloc((size_t)NB_EV * ND * 4));
  float* nb_out = (float*)(ws + alloc((size_t)4 * NB_EV * ND * 4));

  k_prep_weights<<<512, 256, 0, stream>>>(mlp_W1, mlp_W2, gru_w_ih, gru_w_hh,
                                          W1blk, W2blk, wihblk, whhblk, w320);
  k_prep_misc<<<2048, 256, 0, stream>>>(timestamps, t2v_w0, t2v_b0, t2v_w, t2v_b,
                                        srcn, dstn, memory, time_emb, embA0, embB0, nb_out);
  k_edge<<<NB_EV, 64, 0, stream>>>(edge_attrs, enc_W, enc_b, edge_enc);

  k_nbr<<<dim3(ROWS_NB / 64, 2, 1), 256, 0, stream>>>(
      srcn, dstn, memory, neighbor_ids, neighbor_times, neighbor_edge_attrs,
      t2v_w0, t2v_b0, t2v_w, t2v_b, W1blk, W2blk, w320, mlp_b1, mlp_b2, nb_out);

  k_event<<<2 * NB_EV / 64, 256, 0, stream>>>(
      0, embA0, embB0, embA1, ND, embB1, ND, time_emb, edge_enc,
      W1blk, W2blk, w320, mlp_b1, mlp_b2, nb_out,
      wihblk, whhblk, gru_b_ih, gru_b_hh);

  float* outf = (float*)d_out;
  k_event<<<2 * NB_EV / 64, 256, 0, stream>>>(
      1, embA1, embB1, outf, 2 * ND, outf + ND, 2 * ND, time_emb, edge_enc,
      W1blk, W2blk, w320, mlp_b1, mlp_b2, nb_out,
      wihblk, whhblk, gru_b_ih, gru_b_hh);
}